// Round 25
// baseline (698.185 us; speedup 1.0000x reference)
//
#include <hip/hip_runtime.h>
#include <hip/hip_bf16.h>

#define NSUP 20
#define VEC 352
#define HID 352
#define GATES 1408
#define LIN 300
#define L1C 298
#define P1 59
#define L2C 57
#define P2 11
#define NBLK 2048   // grid for grid-stride stats/apply kernels

typedef __attribute__((ext_vector_type(8))) short short8v;
typedef __attribute__((ext_vector_type(4))) float float4v;

__device__ __forceinline__ float sigf(float x) { return 1.0f / (1.0f + __expf(-x)); }
// fast tanh: saturates to +/-1 at extremes without NaN; ~1e-6 rel err vs tanhf
__device__ __forceinline__ float ftanh(float x) { return 2.f / (1.f + __expf(-2.f * x)) - 1.f; }

__device__ __forceinline__ unsigned short f2bf(float x) {
    union { float f; unsigned u; } v; v.f = x;
    unsigned r = v.u + 0x7fffu + ((v.u >> 16) & 1u);
    return (unsigned short)(r >> 16);
}
__device__ __forceinline__ float bf2f(unsigned short s) {
    union { unsigned u; float f; } v; v.u = ((unsigned)s) << 16; return v.f;
}

// ---------------- cast weights to bf16 (plain row-major copies) + w2 transpose ----------------
__global__ __launch_bounds__(256) void cast_weights(
    const float* __restrict__ wihf, const float* __restrict__ wihr,
    const float* __restrict__ whhr, const float* __restrict__ w2,
    unsigned short* __restrict__ Wf, unsigned short* __restrict__ Wr,
    unsigned short* __restrict__ Wh, unsigned short* __restrict__ w2t)
{
    const int NW = GATES * VEC;
    int i = blockIdx.x * 256 + threadIdx.x;
    if (i < NW) Wf[i] = f2bf(wihf[i]);
    else if (i < 2 * NW) Wr[i - NW] = f2bf(wihr[i - NW]);
    else if (i < 3 * NW) Wh[i - 2 * NW] = f2bf(whhr[i - 2 * NW]);
    else if (i < 3 * NW + 5120) {
        int j = i - 3 * NW;
        int kk = j >> 10, c = (j >> 5) & 31, ci = j & 31;
        w2t[j] = f2bf(w2[c * 160 + ci * 5 + kk]);
    }
}

// ---------------- conv1 block body, boundary checks specialized away for interior blocks ----------
// CLO: front pad possible (bb==0).  CHI: tail pad / short positions possible (bb==14).
template<bool CLO, bool CHI>
__device__ __forceinline__ void c1_block(const float* __restrict__ xr, int bb,
    const float* __restrict__ wr, float b, float& sum, float& sq,
    unsigned short* __restrict__ shrow, int c)
{
    float xv[28];
    int base = bb * 20 - 4;
#pragma unroll
    for (int v8 = 0; v8 < 7; ++v8) {
        int bs = base + v8 * 4;
        bool ok = true;
        if (CLO) ok = ok && (bs >= 0);
        if (CHI) ok = ok && (bs + 3 < LIN);
        if (ok) {
            float4 q4 = *(const float4*)(xr + bs);
            xv[v8 * 4 + 0] = q4.x; xv[v8 * 4 + 1] = q4.y;
            xv[v8 * 4 + 2] = q4.z; xv[v8 * 4 + 3] = q4.w;
        } else {
#pragma unroll
            for (int e = 0; e < 4; ++e) {
                int ix = bs + e;
                xv[v8 * 4 + e] = (ix >= 0 && ix < LIN) ? xr[ix] : 0.f;
            }
        }
    }
#pragma unroll
    for (int grp = 0; grp < 4; ++grp) {
        int lo = bb * 4 + grp;
        float m = -1e30f;
#pragma unroll
        for (int d5 = 0; d5 < 5; ++d5) {
            int dj = grp * 5 + d5;
            if (!CHI || (bb * 20 + dj) <= 297) {
                float y = b;
#pragma unroll
                for (int k = 0; k < 5; ++k) y = fmaf(wr[k], xv[dj + 3 + k], y);
                sum += y; sq = fmaf(y, y, sq);
                m = fmaxf(m, y);
            }
        }
        if (!CHI || lo <= 58) shrow[(1 + lo) * 32 + c] = f2bf(m);
    }
}

// ---------------- conv1: stats (atomic) + pooled raw max -> h1 (bf16 [n][64][32], row=l+1) --------
// bb is data-divergent across halves (half0: bb=it, half1: bb=8+it) so control stays uniform.
// Iterations 1-5 and 7 are fully check-free; 0 and 6 carry the boundary specializations.
// launch_bounds(256,8): cap arch VGPR at 64 to restore occupancy (round-24 version: 96 VGPR, 15% occ).
__global__ __launch_bounds__(256, 8) void conv1_pass1(const float* __restrict__ x,
    const float* __restrict__ w, const float* __restrict__ bias,
    float* __restrict__ acc1, unsigned short* __restrict__ h1, int N)
{
    __shared__ unsigned short sh1[4][2048];
    __shared__ float redS[256], redQ[256];
    int t = threadIdx.x;
    int wv = t >> 6, lane = t & 63;
    int c = lane & 31, half = lane >> 5;
    float wr[5];
#pragma unroll
    for (int k = 0; k < 5; ++k) wr[k] = w[c * 5 + k];
    float b = bias[c];
    float sum = 0.f, sq = 0.f;
    int bb0 = half * 8;
    for (int n = blockIdx.x * 4 + wv; n < N; n += gridDim.x * 4) {
        const float* xr = x + (size_t)n * LIN;
        unsigned short* shrow = &sh1[wv][0];
        // it 0: half0 at bb=0 (front pad); half1 at bb=8 (checks pass harmlessly)
        c1_block<true, false>(xr, bb0 + 0, wr, b, sum, sq, shrow, c);
#pragma unroll
        for (int it = 1; it <= 5; ++it)
            c1_block<false, false>(xr, bb0 + it, wr, b, sum, sq, shrow, c);
        // it 6: half1 at bb=14 (tail pad + short positions); half0 at bb=6 (checks pass)
        c1_block<false, true>(xr, bb0 + 6, wr, b, sum, sq, shrow, c);
        // it 7: only half0 (bb=7)
        if (half == 0) c1_block<false, false>(xr, 7, wr, b, sum, sq, shrow, c);
        if (half == 0) shrow[c] = 0;
        else { shrow[60 * 32 + c] = 0; shrow[61 * 32 + c] = 0;
               shrow[62 * 32 + c] = 0; shrow[63 * 32 + c] = 0; }
        __builtin_amdgcn_sched_barrier(0);   // keep LDS writes before flush reads
        unsigned short* hr = h1 + (size_t)n * 2048;
#pragma unroll
        for (int i = 0; i < 4; ++i)
            *(uint4*)(hr + i * 512 + lane * 8) = *(const uint4*)&sh1[wv][i * 512 + lane * 8];
        __builtin_amdgcn_sched_barrier(0);   // flush reads before next-iter overwrites
    }
    redS[t] = sum; redQ[t] = sq;
    __syncthreads();
    if (t < 32) {
        float s = 0.f, q = 0.f;
#pragma unroll
        for (int m = 0; m < 8; ++m) { s += redS[m * 32 + t]; q += redQ[m * 32 + t]; }
        atomicAdd(&acc1[t], s);
        atomicAdd(&acc1[32 + t], q);
    }
}

// ---------------- conv2 FUSED v3: BN1 consts from acc1 in prologue; stats -> atomicAdd acc2.
// Stage h1 tile to LDS with BN1+relu applied, one MFMA pass -> stats + pooled raw(+bias) -> z.
__global__ __launch_bounds__(256) void conv2_fused(const unsigned short* __restrict__ h1,
    const unsigned short* __restrict__ w2t, const float* __restrict__ b2,
    const float* __restrict__ acc1, float count1,
    const float* __restrict__ g1, const float* __restrict__ b1n,
    unsigned short* __restrict__ z, float* __restrict__ acc2, int N)
{
    __shared__ unsigned short hbl[4][64][40];
    __shared__ unsigned short ytb[4][32][66];
    __shared__ float bcv[32], sc1[32], sh1v[32];
    __shared__ float redS[4][32], redQ[4][32];
    int t = threadIdx.x, wv = t >> 6, lane = t & 63;
    int li = lane & 15, grp = lane >> 4;
    if (t < 32) {
        bcv[t] = b2[t];
        double m = (double)acc1[t] / (double)count1;
        double v = (double)acc1[32 + t] / (double)count1 - m * m;
        float istd = (float)(1.0 / sqrt(v + 1e-5));
        float s = istd * g1[t];
        sc1[t] = s; sh1v[t] = b1n[t] - (float)m * s;
    }
    short8v af[5][2];
#pragma unroll
    for (int kk = 0; kk < 5; ++kk)
#pragma unroll
        for (int mf = 0; mf < 2; ++mf)
            af[kk][mf] = *(const short8v*)(w2t + ((kk * 32 + mf * 16 + li) * 32 + grp * 8));
    float bc[2][4];
#pragma unroll
    for (int mf = 0; mf < 2; ++mf)
#pragma unroll
        for (int r = 0; r < 4; ++r) bc[mf][r] = b2[mf * 16 + grp * 4 + r];
    float sum[2][4] = {}, sq[2][4] = {};
    __syncthreads();
    for (int n = blockIdx.x * 4 + wv; n < N; n += gridDim.x * 4) {
        const unsigned short* hb = h1 + (size_t)n * 2048;
        // stage h1 tile: raw -> BN1 + relu (rows 1..59), pads -> 0
#pragma unroll
        for (int i4 = 0; i4 < 4; ++i4) {
            int i = i4 * 64 + lane;
            int row = i >> 2, ch0 = (i & 3) * 8;
            union { uint4 v; unsigned short u[8]; } d, o;
            d.v = *(const uint4*)(hb + row * 32 + ch0);
            if (row >= 1 && row <= 59) {
#pragma unroll
                for (int e = 0; e < 8; ++e) {
                    int c = ch0 + e;
                    float y = fmaf(sc1[c], bf2f(d.u[e]), sh1v[c]);
                    o.u[e] = f2bf(fmaxf(y, 0.f));
                }
            } else {
                o.v = (uint4){0u, 0u, 0u, 0u};
            }
            *(uint4*)&hbl[wv][row][ch0] = o.v;
        }
        __builtin_amdgcn_sched_barrier(0);
#pragma unroll
        for (int lt = 0; lt < 4; ++lt) {
            float4v acc0 = {0.f, 0.f, 0.f, 0.f}, acc1v = {0.f, 0.f, 0.f, 0.f};
#pragma unroll
            for (int kk = 0; kk < 5; ++kk) {
                int row = lt * 16 + li + kk; row = row > 63 ? 63 : row;
                short8v bf = *(const short8v*)&hbl[wv][row][grp * 8];
                acc0 = __builtin_amdgcn_mfma_f32_16x16x32_bf16(af[kk][0], bf, acc0, 0, 0, 0);
                acc1v = __builtin_amdgcn_mfma_f32_16x16x32_bf16(af[kk][1], bf, acc1v, 0, 0, 0);
            }
            if (lt * 16 + li < L2C) {
#pragma unroll
                for (int r = 0; r < 4; ++r) {
                    float y0 = acc0[r] + bc[0][r]; sum[0][r] += y0; sq[0][r] = fmaf(y0, y0, sq[0][r]);
                    float y1 = acc1v[r] + bc[1][r]; sum[1][r] += y1; sq[1][r] = fmaf(y1, y1, sq[1][r]);
                }
            }
#pragma unroll
            for (int r = 0; r < 4; ++r) {
                ytb[wv][grp * 4 + r][lt * 16 + li] = f2bf(acc0[r]);
                ytb[wv][16 + grp * 4 + r][lt * 16 + li] = f2bf(acc1v[r]);
            }
        }
        unsigned short* zr = z + (size_t)n * VEC;
        for (int s = lane; s < VEC; s += 64) {
            int c = s / 11, lo = s % 11;
            float m = bf2f(ytb[wv][c][lo * 5]);
#pragma unroll
            for (int d = 1; d < 5; ++d) m = fmaxf(m, bf2f(ytb[wv][c][lo * 5 + d]));
            zr[s] = f2bf(m + bcv[c]);          // raw pooled + bias; BN2+relu in z_pass2
        }
        __builtin_amdgcn_sched_barrier(0);
    }
#pragma unroll
    for (int mf = 0; mf < 2; ++mf)
#pragma unroll
        for (int r = 0; r < 4; ++r) {
            float s = sum[mf][r], q = sq[mf][r];
#pragma unroll
            for (int m = 1; m < 16; m <<= 1) { s += __shfl_xor(s, m); q += __shfl_xor(q, m); }
            if (li == 0) { redS[wv][mf * 16 + grp * 4 + r] = s; redQ[wv][mf * 16 + grp * 4 + r] = q; }
        }
    __syncthreads();
    if (t < 32) atomicAdd(&acc2[t], redS[0][t] + redS[1][t] + redS[2][t] + redS[3][t]);
    else if (t < 64) atomicAdd(&acc2[t - 32 + 32], redQ[0][t - 32] + redQ[1][t - 32] + redQ[2][t - 32] + redQ[3][t - 32]);
}

// ---------------- z pass2: BN2 consts from acc2 in prologue; in-place BN2+relu on z ----------------
__global__ __launch_bounds__(256) void z_pass2(unsigned short* __restrict__ z,
    const float* __restrict__ acc2, float count2,
    const float* __restrict__ g2, const float* __restrict__ be2, long long total)
{
    __shared__ float sc[32], sh[32];
    int t = threadIdx.x;
    if (t < 32) {
        double m = (double)acc2[t] / (double)count2;
        double v = (double)acc2[32 + t] / (double)count2 - m * m;
        float istd = (float)(1.0 / sqrt(v + 1e-5));
        float s = istd * g2[t];
        sc[t] = s; sh[t] = be2[t] - (float)m * s;
    }
    __syncthreads();
    long long i = (long long)blockIdx.x * 256 + t;
    if (i >= total) return;
    long long n = i / 44; int r = (int)(i % 44);
    unsigned short* p = z + n * VEC + r * 8;
    union { uint4 v; unsigned short u[8]; } d;
    d.v = *(const uint4*)p;
#pragma unroll
    for (int e = 0; e < 8; ++e) {
        int c = (r * 8 + e) / 11;
        float y = fmaf(sc[c], bf2f(d.u[e]), sh[c]);
        d.u[e] = f2bf(fmaxf(y, 0.f));
    }
    *(uint4*)p = d.v;
}

// ---------------- support path (3 launches) ----------------
__global__ __launch_bounds__(128) void sup_a(const unsigned short* __restrict__ z,
    const float* __restrict__ wihf, const float* __restrict__ bihf, const float* __restrict__ bhhf,
    const float* __restrict__ wihr, const float* __restrict__ bihr, const float* __restrict__ bhhr,
    float* __restrict__ misc)
{
    __shared__ float s0[VEC], s1[VEC];
    int t = threadIdx.x, bid = blockIdx.x;
    for (int v = t; v < VEC; v += 128) {
        float a0 = 0.f, a1 = 0.f;
        for (int k = 0; k < 10; ++k) {
            a0 += bf2f(z[(size_t)k * VEC + v]);
            a1 += bf2f(z[(size_t)(10 + k) * VEC + v]);
        }
        s0[v] = a0 * 0.1f; s1[v] = a1 * 0.1f;
    }
    __syncthreads();
    if (bid == 0)
        for (int v = t; v < VEC; v += 128) { misc[128 + v] = s0[v]; misc[480 + v] = s1[v]; }
    if (bid < 11) {
        int j = bid * 128 + t;
        float a = bihf[j] + bhhf[j];
        const float* w = wihf + (size_t)j * VEC;
        for (int k = 0; k < VEC; k += 4)
            a += w[k] * s0[k] + w[k + 1] * s0[k + 1] + w[k + 2] * s0[k + 2] + w[k + 3] * s0[k + 3];
        misc[2240 + j] = a;
    } else {
        int j = (bid - 11) * 128 + t;
        float br = bihr[j] + bhhr[j];
        const float* wr = wihr + (size_t)j * VEC;
        float p1 = br, p0 = br;
        for (int k = 0; k < VEC; k += 4) {
            p1 += wr[k] * s1[k] + wr[k + 1] * s1[k + 1] + wr[k + 2] * s1[k + 2] + wr[k + 3] * s1[k + 3];
            p0 += wr[k] * s0[k] + wr[k + 1] * s0[k + 1] + wr[k + 2] * s0[k + 2] + wr[k + 3] * s0[k + 3];
        }
        misc[6464 + j] = p1;
        misc[7872 + j] = p0;
    }
}

// sup_b: local cell0 -> h1f; mode1 gates; block 0 persists h1f
__global__ __launch_bounds__(128) void sup_b(
    const float* __restrict__ wihf, const float* __restrict__ whhf,
    const float* __restrict__ bihf, const float* __restrict__ bhhf, float* __restrict__ misc)
{
    __shared__ float s1[VEC], h1f[VEC];
    int t = threadIdx.x, bid = blockIdx.x;
    for (int v = t; v < VEC; v += 128) {
        s1[v] = misc[480 + v];
        float iv = sigf(misc[2240 + v]);
        float gv = tanhf(misc[2240 + 704 + v]);
        float ov = sigf(misc[2240 + 1056 + v]);
        h1f[v] = ov * tanhf(iv * gv);
    }
    __syncthreads();
    if (bid == 0)
        for (int v = t; v < VEC; v += 128) misc[832 + v] = h1f[v];
    int j = bid * 128 + t;
    float a = bihf[j] + bhhf[j];
    const float* w = wihf + (size_t)j * VEC;
    const float* wh = whhf + (size_t)j * VEC;
    for (int k = 0; k < VEC; k += 4) {
        a += w[k] * s1[k] + w[k + 1] * s1[k + 1] + w[k + 2] * s1[k + 2] + w[k + 3] * s1[k + 3];
        a += wh[k] * h1f[k] + wh[k + 1] * h1f[k + 1] + wh[k + 2] * h1f[k + 2] + wh[k + 3] * h1f[k + 3];
    }
    misc[3648 + j] = a;
}

// sup_c: local cell0 (c1) + cell1 -> h2f/c2f; gf_const gates; block 0 persists h2f/c2f
__global__ __launch_bounds__(128) void sup_c(
    const float* __restrict__ whhf, const float* __restrict__ bihf,
    const float* __restrict__ bhhf, float* __restrict__ misc)
{
    __shared__ float h2f[VEC];
    int t = threadIdx.x, bid = blockIdx.x;
    for (int v = t; v < VEC; v += 128) {
        float iv0 = sigf(misc[2240 + v]);
        float gv0 = tanhf(misc[2240 + 704 + v]);
        float c1 = iv0 * gv0;
        float iv = sigf(misc[3648 + v]);
        float fv = sigf(misc[3648 + 352 + v]);
        float gv = tanhf(misc[3648 + 704 + v]);
        float ov = sigf(misc[3648 + 1056 + v]);
        float c2 = fv * c1 + iv * gv;
        float hh = ov * tanhf(c2);
        h2f[v] = hh;
        if (bid == 0) { misc[1536 + v] = hh; misc[1888 + v] = c2; }
    }
    __syncthreads();
    int j = bid * 128 + t;
    float a = bihf[j] + bhhf[j];
    const float* wh = whhf + (size_t)j * VEC;
    for (int k = 0; k < VEC; k += 4)
        a += wh[k] * h2f[k] + wh[k + 1] * h2f[k + 1] + wh[k + 2] * h2f[k + 2] + wh[k + 3] * h2f[k + 3];
    misc[5056 + j] = a;
}

// ---------------- W staging: 4 gates x 16 rows x 352 bf16 -> LDS (rows padded to 360, 46KB) ----------------
// Measured local optimum (72.7us). Occupancy-raising variants all regressed:
// 128q acc (r12: 102us), 2-pass 2-gate (r18: 91us), hybrid 2LDS+2global (r21: 81us).
__device__ __forceinline__ void stage_W(const unsigned short* __restrict__ Wb, int h0, int t,
                                        unsigned short (*Wlds)[16][360])
{
    for (int i = t; i < 2816; i += 256) {
        int gate = i / 704, rem = i - gate * 704;
        int row = rem / 44, ch = rem - row * 44;
        *(uint4*)&Wlds[gate][row][ch * 8] =
            *(const uint4*)(Wb + ((size_t)gate * HID + h0 + row) * VEC + ch * 8);
    }
}

// GEMM core reading W from LDS: 4 global X loads + 4 LDS W reads -> 16 MFMA per K-step.
__device__ __forceinline__ void lstm_gemm_lds(
    const unsigned short* __restrict__ Xb,
    const unsigned short (*Wlds)[16][360],
    int q0, int li, int grp, int Q, float4v acc[4][4])
{
    const unsigned short* xp[4];
#pragma unroll
    for (int mf = 0; mf < 4; ++mf) {
        int qr = q0 + mf * 16 + li;
        if (qr > Q - 1) qr = Q - 1;
        xp[mf] = Xb + (size_t)qr * VEC + grp * 8;
    }
#pragma unroll
    for (int gi = 0; gi < 4; ++gi)
#pragma unroll
        for (int mf = 0; mf < 4; ++mf) acc[gi][mf] = (float4v){0.f, 0.f, 0.f, 0.f};
#pragma unroll 2
    for (int ks = 0; ks < 11; ++ks) {
        int ko = ks * 32;
        short8v a0 = *(const short8v*)(xp[0] + ko);
        short8v a1 = *(const short8v*)(xp[1] + ko);
        short8v a2 = *(const short8v*)(xp[2] + ko);
        short8v a3 = *(const short8v*)(xp[3] + ko);
        short8v b0 = *(const short8v*)&Wlds[0][li][ko + grp * 8];
        short8v b1 = *(const short8v*)&Wlds[1][li][ko + grp * 8];
        short8v b2 = *(const short8v*)&Wlds[2][li][ko + grp * 8];
        short8v b3 = *(const short8v*)&Wlds[3][li][ko + grp * 8];
        acc[0][0] = __builtin_amdgcn_mfma_f32_16x16x32_bf16(a0, b0, acc[0][0], 0, 0, 0);
        acc[0][1] = __builtin_amdgcn_mfma_f32_16x16x32_bf16(a1, b0, acc[0][1], 0, 0, 0);
        acc[0][2] = __builtin_amdgcn_mfma_f32_16x16x32_bf16(a2, b0, acc[0][2], 0, 0, 0);
        acc[0][3] = __builtin_amdgcn_mfma_f32_16x16x32_bf16(a3, b0, acc[0][3], 0, 0, 0);
        acc[1][0] = __builtin_amdgcn_mfma_f32_16x16x32_bf16(a0, b1, acc[1][0], 0, 0, 0);
        acc[1][1] = __builtin_amdgcn_mfma_f32_16x16x32_bf16(a1, b1, acc[1][1], 0, 0, 0);
        acc[1][2] = __builtin_amdgcn_mfma_f32_16x16x32_bf16(a2, b1, acc[1][2], 0, 0, 0);
        acc[1][3] = __builtin_amdgcn_mfma_f32_16x16x32_bf16(a3, b1, acc[1][3], 0, 0, 0);
        acc[2][0] = __builtin_amdgcn_mfma_f32_16x16x32_bf16(a0, b2, acc[2][0], 0, 0, 0);
        acc[2][1] = __builtin_amdgcn_mfma_f32_16x16x32_bf16(a1, b2, acc[2][1], 0, 0, 0);
        acc[2][2] = __builtin_amdgcn_mfma_f32_16x16x32_bf16(a2, b2, acc[2][2], 0, 0, 0);
        acc[2][3] = __builtin_amdgcn_mfma_f32_16x16x32_bf16(a3, b2, acc[2][3], 0, 0, 0);
        acc[3][0] = __builtin_amdgcn_mfma_f32_16x16x32_bf16(a0, b3, acc[3][0], 0, 0, 0);
        acc[3][1] = __builtin_amdgcn_mfma_f32_16x16x32_bf16(a1, b3, acc[3][1], 0, 0, 0);
        acc[3][2] = __builtin_amdgcn_mfma_f32_16x16x32_bf16(a2, b3, acc[3][2], 0, 0, 0);
        acc[3][3] = __builtin_amdgcn_mfma_f32_16x16x32_bf16(a3, b3, acc[3][3], 0, 0, 0);
    }
}

// ---------------- dual first-step kernel: y<22 -> fwd step2 (Wf), y>=22 -> bwd step0 (Wr) ----------------
__global__ __launch_bounds__(256, 4) void lstm_dual(
    const unsigned short* __restrict__ zq,
    const unsigned short* __restrict__ Wf, const unsigned short* __restrict__ Wr,
    const float* __restrict__ misc, const float* __restrict__ bihr, const float* __restrict__ bhhr,
    unsigned short* __restrict__ h3fb, unsigned short* __restrict__ hb1b,
    unsigned short* __restrict__ cb1b, int Q)
{
    __shared__ unsigned short Wlds[4][16][360];
    int t = threadIdx.x, wv = t >> 6, lane = t & 63;
    int li = lane & 15, grp = lane >> 4;
    int q0 = blockIdx.x * 256 + wv * 64;
    int fwd = (blockIdx.y < 22);
    int h0 = (fwd ? blockIdx.y : blockIdx.y - 22) * 16;
    int h = h0 + li;
    stage_W(fwd ? Wf : Wr, h0, t, Wlds);
    __syncthreads();
    float4v acc[4][4];
    lstm_gemm_lds(zq, Wlds, q0, li, grp, Q, acc);
    if (fwd) {
        float ai = misc[5056 + h], afv = misc[5056 + HID + h];
        float ag = misc[5056 + 2 * HID + h], ao = misc[5056 + 3 * HID + h];
        float cc1 = misc[1888 + h];
#pragma unroll
        for (int mf = 0; mf < 4; ++mf)
#pragma unroll
            for (int r = 0; r < 4; ++r) {
                int q = q0 + mf * 16 + grp * 4 + r;
                if (q >= Q) continue;
                float iv = sigf(acc[0][mf][r] + ai);
                float fv = sigf(acc[1][mf][r] + afv);
                float gv = ftanh(acc[2][mf][r] + ag);
                float ov = sigf(acc[3][mf][r] + ao);
                float cn = fmaf(fv, cc1, iv * gv);
                h3fb[(size_t)q * HID + h] = f2bf(ov * ftanh(cn));
            }
    } else {
        float ai = bihr[h] + bhhr[h];
        float ag = bihr[2 * HID + h] + bhhr[2 * HID + h];
        float ao = bihr[3 * HID + h] + bhhr[3 * HID + h];
#pragma unroll
        for (int mf = 0; mf < 4; ++mf)
#pragma unroll
            for (int r = 0; r < 4; ++r) {
                int q = q0 + mf * 16 + grp * 4 + r;
                if (q >= Q) continue;
                float iv = sigf(acc[0][mf][r] + ai);
                float gv = ftanh(acc[2][mf][r] + ag);
                float ov = sigf(acc[3][mf][r] + ao);
                float cn = iv * gv;
                hb1b[(size_t)q * HID + h] = f2bf(ov * ftanh(cn));
                cb1b[(size_t)q * HID + h] = f2bf(cn);
            }
    }
}

// ---------------- recurrent LSTM step: gates = hprev@Wh + add1 ; cprev bf16 per-q ----------------
__global__ __launch_bounds__(256, 4) void lstm_mfma(
    const unsigned short* __restrict__ Xb, const unsigned short* __restrict__ Wb,
    const float* __restrict__ add1, const unsigned short* __restrict__ cprevb,
    unsigned short* __restrict__ hbf, unsigned short* __restrict__ cbf, int Q)
{
    __shared__ unsigned short Wlds[4][16][360];
    int t = threadIdx.x, wv = t >> 6, lane = t & 63;
    int li = lane & 15, grp = lane >> 4;
    int q0 = blockIdx.x * 256 + wv * 64;
    int h0 = blockIdx.y * 16;
    int h = h0 + li;
    stage_W(Wb, h0, t, Wlds);
    __syncthreads();
    float4v acc[4][4];
    lstm_gemm_lds(Xb, Wlds, q0, li, grp, Q, acc);
    float ai = add1[h], afv = add1[HID + h], ag = add1[2 * HID + h], ao = add1[3 * HID + h];
#pragma unroll
    for (int mf = 0; mf < 4; ++mf) {
#pragma unroll
        for (int r = 0; r < 4; ++r) {
            int q = q0 + mf * 16 + grp * 4 + r;
            if (q >= Q) continue;
            float iv = sigf(acc[0][mf][r] + ai);
            float fv = sigf(acc[1][mf][r] + afv);
            float gv = ftanh(acc[2][mf][r] + ag);
            float ov = sigf(acc[3][mf][r] + ao);
            float cp = bf2f(cprevb[(size_t)q * HID + h]);
            float cn = fmaf(fv, cp, iv * gv);
            float hn = ov * ftanh(cn);
            hbf[(size_t)q * HID + h] = f2bf(hn);
            if (cbf) cbf[(size_t)q * HID + h] = f2bf(cn);
        }
    }
}

// ---------------- cosine sims + softmax; one wave per query (bf16 h inputs) ----------------
__global__ __launch_bounds__(256) void final_sims(
    const unsigned short* __restrict__ h3f, const unsigned short* __restrict__ hb1,
    const unsigned short* __restrict__ hb2, const unsigned short* __restrict__ hb3,
    const float* __restrict__ misc, float* __restrict__ out, int Q)
{
    int t = threadIdx.x;
    int wave = t >> 6, lane = t & 63;
    int q = blockIdx.x * 4 + wave;
    if (q >= Q) return;
    const unsigned short* a3 = h3f + (size_t)q * HID;
    const unsigned short* b1 = hb1 + (size_t)q * HID;
    const unsigned short* b2 = hb2 + (size_t)q * HID;
    const unsigned short* b3 = hb3 + (size_t)q * HID;
    const float* h1c = misc + 832;
    const float* h2c = misc + 1536;
    float sA = 0, sB = 0, s3 = 0, s4 = 0, s5 = 0, s6 = 0, s7 = 0, s8 = 0, s9 = 0, s10 = 0;
    for (int hh = lane; hh < HID; hh += 64) {
        float a = bf2f(a3[hh]), b = bf2f(b1[hh]), v2 = bf2f(b2[hh]), v3 = bf2f(b3[hh]);
        float u1 = h1c[hh], u2 = h2c[hh];
        sA += u1 * a;  sB += u2 * a;
        s3 += a * a;   s4 += b * b;
        s5 += v3 * b;  s6 += v2 * b;
        s7 += v3 * v3; s8 += v2 * v2;
        s9 += u1 * u1; s10 += u2 * u2;
    }
#pragma unroll
    for (int off = 32; off > 0; off >>= 1) {
        sA += __shfl_xor(sA, off);  sB += __shfl_xor(sB, off);
        s3 += __shfl_xor(s3, off);  s4 += __shfl_xor(s4, off);
        s5 += __shfl_xor(s5, off);  s6 += __shfl_xor(s6, off);
        s7 += __shfl_xor(s7, off);  s8 += __shfl_xor(s8, off);
        s9 += __shfl_xor(s9, off);  s10 += __shfl_xor(s10, off);
    }
    if (lane == 0) {
        float nq  = fmaxf(sqrtf(s3 + s4), 1e-8f);
        float ns0 = fmaxf(sqrtf(s9 + s7), 1e-8f);
        float ns1 = fmaxf(sqrtf(s10 + s8), 1e-8f);
        float sim0 = (sA + s5) / (ns0 * nq);
        float sim1 = (sB + s6) / (ns1 * nq);
        float mx = fmaxf(sim0, sim1);
        float e0 = __expf(sim0 - mx), e1 = __expf(sim1 - mx);
        float inv = 1.f / (e0 + e1);
        out[(size_t)q * 2 + 0] = e0 * inv;
        out[(size_t)q * 2 + 1] = e1 * inv;
    }
}

extern "C" void kernel_launch(void* const* d_in, const int* in_sizes, int n_in,
                              void* d_out, int out_size, void* d_ws, size_t ws_size,
                              hipStream_t stream)
{
    const float* x    = (const float*)d_in[0];
    const float* c1w  = (const float*)d_in[1];
    const float* c1b  = (const float*)d_in[2];
    const float* bn1g = (const float*)d_in[3];
    const float* bn1b = (const float*)d_in[4];
    const float* c2w  = (const float*)d_in[5];
    const float* c2b  = (const float*)d_in[6];
    const float* bn2g = (const float*)d_in[7];
    const float* bn2b = (const float*)d_in[8];
    const float* wihf = (const float*)d_in[9];
    const float* whhf = (const float*)d_in[10];
    const float* bihf = (const float*)d_in[11];
    const float* bhhf = (const float*)d_in[12];
    const float* wihr = (const float*)d_in[13];
    const float* whhr = (const float*)d_in[14];
    const float* bihr = (const float*)d_in[15];
    const float* bhhr = (const float*)d_in[16];

    int N = in_sizes[0] / LIN;
    int Q = N - NSUP;

    char* ws = (char*)d_ws;
    float* acc1  = (float*)(ws + 0);                       // 64 f32 stats accumulators (conv1)
    float* acc2  = (float*)(ws + 256);                     // 64 f32 stats accumulators (conv2)
    float* misc  = (float*)(ws + 1048576);                 // ~10.7K f32
    unsigned short* w2t = (unsigned short*)(ws + 1114112); // 5120 bf16
    unsigned short* Wf  = (unsigned short*)(ws + 2097152); // 1408*352 bf16
    unsigned short* Wr  = (unsigned short*)(ws + 3145728);
    unsigned short* Wh  = (unsigned short*)(ws + 4194304);
    unsigned short* z   = (unsigned short*)(ws + 5242880); // N*352 bf16
    unsigned short* h1  = (unsigned short*)(ws + 17825792);// N*64*32 bf16 (dead after conv2)
    const size_t Sb = (size_t)Q * HID * sizeof(unsigned short);   // ~11.5MB
    unsigned short* h3fb = (unsigned short*)(ws + 17825792);      // over h1 (dead)
    unsigned short* hb1b = (unsigned short*)(ws + 17825792 + Sb);
    unsigned short* cb1b = (unsigned short*)(ws + 17825792 + 2 * Sb);
    unsigned short* hb2b = (unsigned short*)(ws + 17825792 + 3 * Sb);
    unsigned short* cb2b = (unsigned short*)(ws + 17825792 + 4 * Sb);
    unsigned short* hb3b = (unsigned short*)(ws + 17825792 + 5 * Sb);

    // 0. zero the stats accumulators (capture-safe async memset)
    hipMemsetAsync(acc1, 0, 512, stream);
    // 1. cast weights
    {
        int tot = 3 * GATES * VEC + 5120;
        cast_weights<<<(tot + 255) / 256, 256, 0, stream>>>(wihf, wihr, whhr, c2w, Wf, Wr, Wh, w2t);
    }
    // 2. conv1: stats (atomic) + pooled raw, boundary-specialized blocks, 64-VGPR cap
    conv1_pass1<<<NBLK, 256, 0, stream>>>(x, c1w, c1b, acc1, h1, N);
    // 3. conv2 fused: BN1 consts from acc1; stage h1+BN1+relu in LDS, one MFMA pass -> acc2 + raw z
    conv2_fused<<<NBLK, 256, 0, stream>>>(h1, w2t, c2b, acc1, (float)((long long)N * L1C),
                                          bn1g, bn1b, z, acc2, N);
    // 4. z BN2+relu in place (BN2 consts from acc2)
    {
        long long total = (long long)N * 44;
        z_pass2<<<(unsigned)((total + 255) / 256), 256, 0, stream>>>(z, acc2, (float)((long long)N * L2C),
                                                                     bn2g, bn2b, total);
    }
    // 5. support path (3 launches)
    sup_a<<<22, 128, 0, stream>>>(z, wihf, bihf, bhhf, wihr, bihr, bhhr, misc);
    sup_b<<<11, 128, 0, stream>>>(wihf, whhf, bihf, bhhf, misc);
    sup_c<<<11, 128, 0, stream>>>(whhf, bihf, bhhf, misc);
    // 6. big LSTM steps (bf16 h/c state), 64q per wave / 256q per block, W staged via LDS
    const unsigned short* zq = z + (size_t)NSUP * VEC;
    int gx = (Q + 255) / 256;
    lstm_dual<<<dim3(gx, 44), 256, 0, stream>>>(zq, Wf, Wr, misc, bihr, bhhr, h3fb, hb1b, cb1b, Q);
    lstm_mfma<<<dim3(gx, 22), 256, 0, stream>>>(hb1b, Wh, misc + 6464, cb1b, hb2b, cb2b, Q);
    lstm_mfma<<<dim3(gx, 22), 256, 0, stream>>>(hb2b, Wh, misc + 7872, cb2b, hb3b, nullptr, Q);
    // 7. sims + softmax
    final_sims<<<(Q + 3) / 4, 256, 0, stream>>>(h3fb, hb1b, hb2b, hb3b, misc, (float*)d_out, Q);
}

// Round 26
// 354.931 us; speedup vs baseline: 1.9671x; 1.9671x over previous
//
#include <hip/hip_runtime.h>
#include <hip/hip_bf16.h>

#define NSUP 20
#define VEC 352
#define HID 352
#define GATES 1408
#define LIN 300
#define L1C 298
#define P1 59
#define L2C 57
#define P2 11
#define NBLK 2048   // grid for grid-stride stats/apply kernels

typedef __attribute__((ext_vector_type(8))) short short8v;
typedef __attribute__((ext_vector_type(4))) float float4v;

__device__ __forceinline__ float sigf(float x) { return 1.0f / (1.0f + __expf(-x)); }
// fast tanh: saturates to +/-1 at extremes without NaN; ~1e-6 rel err vs tanhf
__device__ __forceinline__ float ftanh(float x) { return 2.f / (1.f + __expf(-2.f * x)) - 1.f; }

__device__ __forceinline__ unsigned short f2bf(float x) {
    union { float f; unsigned u; } v; v.f = x;
    unsigned r = v.u + 0x7fffu + ((v.u >> 16) & 1u);
    return (unsigned short)(r >> 16);
}
__device__ __forceinline__ float bf2f(unsigned short s) {
    union { unsigned u; float f; } v; v.u = ((unsigned)s) << 16; return v.f;
}

// ---------------- cast weights to bf16 (plain row-major copies) + w2 transpose ----------------
__global__ __launch_bounds__(256) void cast_weights(
    const float* __restrict__ wihf, const float* __restrict__ wihr,
    const float* __restrict__ whhr, const float* __restrict__ w2,
    unsigned short* __restrict__ Wf, unsigned short* __restrict__ Wr,
    unsigned short* __restrict__ Wh, unsigned short* __restrict__ w2t)
{
    const int NW = GATES * VEC;
    int i = blockIdx.x * 256 + threadIdx.x;
    if (i < NW) Wf[i] = f2bf(wihf[i]);
    else if (i < 2 * NW) Wr[i - NW] = f2bf(wihr[i - NW]);
    else if (i < 3 * NW) Wh[i - 2 * NW] = f2bf(whhr[i - 2 * NW]);
    else if (i < 3 * NW + 5120) {
        int j = i - 3 * NW;
        int kk = j >> 10, c = (j >> 5) & 31, ci = j & 31;
        w2t[j] = f2bf(w2[c * 160 + ci * 5 + kk]);
    }
}

// ---------------- conv1 block body, boundary checks specialized away for interior blocks ----------
// CLO: front pad possible (bb==0).  CHI: tail pad / short positions possible (bb==14).
template<bool CLO, bool CHI>
__device__ __forceinline__ void c1_block(const float* __restrict__ xr, int bb,
    const float* __restrict__ wr, float b, float& sum, float& sq,
    unsigned short* __restrict__ shrow, int c)
{
    float xv[28];
    int base = bb * 20 - 4;
#pragma unroll
    for (int v8 = 0; v8 < 7; ++v8) {
        int bs = base + v8 * 4;
        bool ok = true;
        if (CLO) ok = ok && (bs >= 0);
        if (CHI) ok = ok && (bs + 3 < LIN);
        if (ok) {
            float4 q4 = *(const float4*)(xr + bs);
            xv[v8 * 4 + 0] = q4.x; xv[v8 * 4 + 1] = q4.y;
            xv[v8 * 4 + 2] = q4.z; xv[v8 * 4 + 3] = q4.w;
        } else {
#pragma unroll
            for (int e = 0; e < 4; ++e) {
                int ix = bs + e;
                xv[v8 * 4 + e] = (ix >= 0 && ix < LIN) ? xr[ix] : 0.f;
            }
        }
    }
#pragma unroll
    for (int grp = 0; grp < 4; ++grp) {
        int lo = bb * 4 + grp;
        float m = -1e30f;
#pragma unroll
        for (int d5 = 0; d5 < 5; ++d5) {
            int dj = grp * 5 + d5;
            if (!CHI || (bb * 20 + dj) <= 297) {
                float y = b;
#pragma unroll
                for (int k = 0; k < 5; ++k) y = fmaf(wr[k], xv[dj + 3 + k], y);
                sum += y; sq = fmaf(y, y, sq);
                m = fmaxf(m, y);
            }
        }
        if (!CHI || lo <= 58) shrow[(1 + lo) * 32 + c] = f2bf(m);
    }
}

// ---------------- conv1: stats (atomic) + pooled raw max -> h1 (bf16 [n][64][32], row=l+1) --------
// bb is data-divergent across halves (half0: bb=it, half1: bb=8+it) so control stays uniform.
// Iterations 1-5 and 7 are fully check-free; 0 and 6 carry the boundary specializations.
// NO launch_bounds cap: live set ~90 VGPR; (256,8) cap -> scratch spill, 416us (r25). 96 VGPR free = 74.9us.
__global__ __launch_bounds__(256) void conv1_pass1(const float* __restrict__ x,
    const float* __restrict__ w, const float* __restrict__ bias,
    float* __restrict__ acc1, unsigned short* __restrict__ h1, int N)
{
    __shared__ unsigned short sh1[4][2048];
    __shared__ float redS[256], redQ[256];
    int t = threadIdx.x;
    int wv = t >> 6, lane = t & 63;
    int c = lane & 31, half = lane >> 5;
    float wr[5];
#pragma unroll
    for (int k = 0; k < 5; ++k) wr[k] = w[c * 5 + k];
    float b = bias[c];
    float sum = 0.f, sq = 0.f;
    int bb0 = half * 8;
    for (int n = blockIdx.x * 4 + wv; n < N; n += gridDim.x * 4) {
        const float* xr = x + (size_t)n * LIN;
        unsigned short* shrow = &sh1[wv][0];
        // it 0: half0 at bb=0 (front pad); half1 at bb=8 (checks pass harmlessly)
        c1_block<true, false>(xr, bb0 + 0, wr, b, sum, sq, shrow, c);
#pragma unroll
        for (int it = 1; it <= 5; ++it)
            c1_block<false, false>(xr, bb0 + it, wr, b, sum, sq, shrow, c);
        // it 6: half1 at bb=14 (tail pad + short positions); half0 at bb=6 (checks pass)
        c1_block<false, true>(xr, bb0 + 6, wr, b, sum, sq, shrow, c);
        // it 7: only half0 (bb=7)
        if (half == 0) c1_block<false, false>(xr, 7, wr, b, sum, sq, shrow, c);
        if (half == 0) shrow[c] = 0;
        else { shrow[60 * 32 + c] = 0; shrow[61 * 32 + c] = 0;
               shrow[62 * 32 + c] = 0; shrow[63 * 32 + c] = 0; }
        __builtin_amdgcn_sched_barrier(0);   // keep LDS writes before flush reads
        unsigned short* hr = h1 + (size_t)n * 2048;
#pragma unroll
        for (int i = 0; i < 4; ++i)
            *(uint4*)(hr + i * 512 + lane * 8) = *(const uint4*)&sh1[wv][i * 512 + lane * 8];
        __builtin_amdgcn_sched_barrier(0);   // flush reads before next-iter overwrites
    }
    redS[t] = sum; redQ[t] = sq;
    __syncthreads();
    if (t < 32) {
        float s = 0.f, q = 0.f;
#pragma unroll
        for (int m = 0; m < 8; ++m) { s += redS[m * 32 + t]; q += redQ[m * 32 + t]; }
        atomicAdd(&acc1[t], s);
        atomicAdd(&acc1[32 + t], q);
    }
}

// ---------------- conv2 FUSED v3: BN1 consts from acc1 in prologue; stats -> atomicAdd acc2.
// Stage h1 tile to LDS with BN1+relu applied, one MFMA pass -> stats + pooled raw(+bias) -> z.
__global__ __launch_bounds__(256) void conv2_fused(const unsigned short* __restrict__ h1,
    const unsigned short* __restrict__ w2t, const float* __restrict__ b2,
    const float* __restrict__ acc1, float count1,
    const float* __restrict__ g1, const float* __restrict__ b1n,
    unsigned short* __restrict__ z, float* __restrict__ acc2, int N)
{
    __shared__ unsigned short hbl[4][64][40];
    __shared__ unsigned short ytb[4][32][66];
    __shared__ float bcv[32], sc1[32], sh1v[32];
    __shared__ float redS[4][32], redQ[4][32];
    int t = threadIdx.x, wv = t >> 6, lane = t & 63;
    int li = lane & 15, grp = lane >> 4;
    if (t < 32) {
        bcv[t] = b2[t];
        double m = (double)acc1[t] / (double)count1;
        double v = (double)acc1[32 + t] / (double)count1 - m * m;
        float istd = (float)(1.0 / sqrt(v + 1e-5));
        float s = istd * g1[t];
        sc1[t] = s; sh1v[t] = b1n[t] - (float)m * s;
    }
    short8v af[5][2];
#pragma unroll
    for (int kk = 0; kk < 5; ++kk)
#pragma unroll
        for (int mf = 0; mf < 2; ++mf)
            af[kk][mf] = *(const short8v*)(w2t + ((kk * 32 + mf * 16 + li) * 32 + grp * 8));
    float bc[2][4];
#pragma unroll
    for (int mf = 0; mf < 2; ++mf)
#pragma unroll
        for (int r = 0; r < 4; ++r) bc[mf][r] = b2[mf * 16 + grp * 4 + r];
    float sum[2][4] = {}, sq[2][4] = {};
    __syncthreads();
    for (int n = blockIdx.x * 4 + wv; n < N; n += gridDim.x * 4) {
        const unsigned short* hb = h1 + (size_t)n * 2048;
        // stage h1 tile: raw -> BN1 + relu (rows 1..59), pads -> 0
#pragma unroll
        for (int i4 = 0; i4 < 4; ++i4) {
            int i = i4 * 64 + lane;
            int row = i >> 2, ch0 = (i & 3) * 8;
            union { uint4 v; unsigned short u[8]; } d, o;
            d.v = *(const uint4*)(hb + row * 32 + ch0);
            if (row >= 1 && row <= 59) {
#pragma unroll
                for (int e = 0; e < 8; ++e) {
                    int c = ch0 + e;
                    float y = fmaf(sc1[c], bf2f(d.u[e]), sh1v[c]);
                    o.u[e] = f2bf(fmaxf(y, 0.f));
                }
            } else {
                o.v = (uint4){0u, 0u, 0u, 0u};
            }
            *(uint4*)&hbl[wv][row][ch0] = o.v;
        }
        __builtin_amdgcn_sched_barrier(0);
#pragma unroll
        for (int lt = 0; lt < 4; ++lt) {
            float4v acc0 = {0.f, 0.f, 0.f, 0.f}, acc1v = {0.f, 0.f, 0.f, 0.f};
#pragma unroll
            for (int kk = 0; kk < 5; ++kk) {
                int row = lt * 16 + li + kk; row = row > 63 ? 63 : row;
                short8v bf = *(const short8v*)&hbl[wv][row][grp * 8];
                acc0 = __builtin_amdgcn_mfma_f32_16x16x32_bf16(af[kk][0], bf, acc0, 0, 0, 0);
                acc1v = __builtin_amdgcn_mfma_f32_16x16x32_bf16(af[kk][1], bf, acc1v, 0, 0, 0);
            }
            if (lt * 16 + li < L2C) {
#pragma unroll
                for (int r = 0; r < 4; ++r) {
                    float y0 = acc0[r] + bc[0][r]; sum[0][r] += y0; sq[0][r] = fmaf(y0, y0, sq[0][r]);
                    float y1 = acc1v[r] + bc[1][r]; sum[1][r] += y1; sq[1][r] = fmaf(y1, y1, sq[1][r]);
                }
            }
#pragma unroll
            for (int r = 0; r < 4; ++r) {
                ytb[wv][grp * 4 + r][lt * 16 + li] = f2bf(acc0[r]);
                ytb[wv][16 + grp * 4 + r][lt * 16 + li] = f2bf(acc1v[r]);
            }
        }
        unsigned short* zr = z + (size_t)n * VEC;
        for (int s = lane; s < VEC; s += 64) {
            int c = s / 11, lo = s % 11;
            float m = bf2f(ytb[wv][c][lo * 5]);
#pragma unroll
            for (int d = 1; d < 5; ++d) m = fmaxf(m, bf2f(ytb[wv][c][lo * 5 + d]));
            zr[s] = f2bf(m + bcv[c]);          // raw pooled + bias; BN2+relu in z_pass2
        }
        __builtin_amdgcn_sched_barrier(0);
    }
#pragma unroll
    for (int mf = 0; mf < 2; ++mf)
#pragma unroll
        for (int r = 0; r < 4; ++r) {
            float s = sum[mf][r], q = sq[mf][r];
#pragma unroll
            for (int m = 1; m < 16; m <<= 1) { s += __shfl_xor(s, m); q += __shfl_xor(q, m); }
            if (li == 0) { redS[wv][mf * 16 + grp * 4 + r] = s; redQ[wv][mf * 16 + grp * 4 + r] = q; }
        }
    __syncthreads();
    if (t < 32) atomicAdd(&acc2[t], redS[0][t] + redS[1][t] + redS[2][t] + redS[3][t]);
    else if (t < 64) atomicAdd(&acc2[t - 32 + 32], redQ[0][t - 32] + redQ[1][t - 32] + redQ[2][t - 32] + redQ[3][t - 32]);
}

// ---------------- z pass2: BN2 consts from acc2 in prologue; in-place BN2+relu on z ----------------
__global__ __launch_bounds__(256) void z_pass2(unsigned short* __restrict__ z,
    const float* __restrict__ acc2, float count2,
    const float* __restrict__ g2, const float* __restrict__ be2, long long total)
{
    __shared__ float sc[32], sh[32];
    int t = threadIdx.x;
    if (t < 32) {
        double m = (double)acc2[t] / (double)count2;
        double v = (double)acc2[32 + t] / (double)count2 - m * m;
        float istd = (float)(1.0 / sqrt(v + 1e-5));
        float s = istd * g2[t];
        sc[t] = s; sh[t] = be2[t] - (float)m * s;
    }
    __syncthreads();
    long long i = (long long)blockIdx.x * 256 + t;
    if (i >= total) return;
    long long n = i / 44; int r = (int)(i % 44);
    unsigned short* p = z + n * VEC + r * 8;
    union { uint4 v; unsigned short u[8]; } d;
    d.v = *(const uint4*)p;
#pragma unroll
    for (int e = 0; e < 8; ++e) {
        int c = (r * 8 + e) / 11;
        float y = fmaf(sc[c], bf2f(d.u[e]), sh[c]);
        d.u[e] = f2bf(fmaxf(y, 0.f));
    }
    *(uint4*)p = d.v;
}

// ---------------- support path (3 launches) ----------------
__global__ __launch_bounds__(128) void sup_a(const unsigned short* __restrict__ z,
    const float* __restrict__ wihf, const float* __restrict__ bihf, const float* __restrict__ bhhf,
    const float* __restrict__ wihr, const float* __restrict__ bihr, const float* __restrict__ bhhr,
    float* __restrict__ misc)
{
    __shared__ float s0[VEC], s1[VEC];
    int t = threadIdx.x, bid = blockIdx.x;
    for (int v = t; v < VEC; v += 128) {
        float a0 = 0.f, a1 = 0.f;
        for (int k = 0; k < 10; ++k) {
            a0 += bf2f(z[(size_t)k * VEC + v]);
            a1 += bf2f(z[(size_t)(10 + k) * VEC + v]);
        }
        s0[v] = a0 * 0.1f; s1[v] = a1 * 0.1f;
    }
    __syncthreads();
    if (bid == 0)
        for (int v = t; v < VEC; v += 128) { misc[128 + v] = s0[v]; misc[480 + v] = s1[v]; }
    if (bid < 11) {
        int j = bid * 128 + t;
        float a = bihf[j] + bhhf[j];
        const float* w = wihf + (size_t)j * VEC;
        for (int k = 0; k < VEC; k += 4)
            a += w[k] * s0[k] + w[k + 1] * s0[k + 1] + w[k + 2] * s0[k + 2] + w[k + 3] * s0[k + 3];
        misc[2240 + j] = a;
    } else {
        int j = (bid - 11) * 128 + t;
        float br = bihr[j] + bhhr[j];
        const float* wr = wihr + (size_t)j * VEC;
        float p1 = br, p0 = br;
        for (int k = 0; k < VEC; k += 4) {
            p1 += wr[k] * s1[k] + wr[k + 1] * s1[k + 1] + wr[k + 2] * s1[k + 2] + wr[k + 3] * s1[k + 3];
            p0 += wr[k] * s0[k] + wr[k + 1] * s0[k + 1] + wr[k + 2] * s0[k + 2] + wr[k + 3] * s0[k + 3];
        }
        misc[6464 + j] = p1;
        misc[7872 + j] = p0;
    }
}

// sup_b: local cell0 -> h1f; mode1 gates; block 0 persists h1f
__global__ __launch_bounds__(128) void sup_b(
    const float* __restrict__ wihf, const float* __restrict__ whhf,
    const float* __restrict__ bihf, const float* __restrict__ bhhf, float* __restrict__ misc)
{
    __shared__ float s1[VEC], h1f[VEC];
    int t = threadIdx.x, bid = blockIdx.x;
    for (int v = t; v < VEC; v += 128) {
        s1[v] = misc[480 + v];
        float iv = sigf(misc[2240 + v]);
        float gv = tanhf(misc[2240 + 704 + v]);
        float ov = sigf(misc[2240 + 1056 + v]);
        h1f[v] = ov * tanhf(iv * gv);
    }
    __syncthreads();
    if (bid == 0)
        for (int v = t; v < VEC; v += 128) misc[832 + v] = h1f[v];
    int j = bid * 128 + t;
    float a = bihf[j] + bhhf[j];
    const float* w = wihf + (size_t)j * VEC;
    const float* wh = whhf + (size_t)j * VEC;
    for (int k = 0; k < VEC; k += 4) {
        a += w[k] * s1[k] + w[k + 1] * s1[k + 1] + w[k + 2] * s1[k + 2] + w[k + 3] * s1[k + 3];
        a += wh[k] * h1f[k] + wh[k + 1] * h1f[k + 1] + wh[k + 2] * h1f[k + 2] + wh[k + 3] * h1f[k + 3];
    }
    misc[3648 + j] = a;
}

// sup_c: local cell0 (c1) + cell1 -> h2f/c2f; gf_const gates; block 0 persists h2f/c2f
__global__ __launch_bounds__(128) void sup_c(
    const float* __restrict__ whhf, const float* __restrict__ bihf,
    const float* __restrict__ bhhf, float* __restrict__ misc)
{
    __shared__ float h2f[VEC];
    int t = threadIdx.x, bid = blockIdx.x;
    for (int v = t; v < VEC; v += 128) {
        float iv0 = sigf(misc[2240 + v]);
        float gv0 = tanhf(misc[2240 + 704 + v]);
        float c1 = iv0 * gv0;
        float iv = sigf(misc[3648 + v]);
        float fv = sigf(misc[3648 + 352 + v]);
        float gv = tanhf(misc[3648 + 704 + v]);
        float ov = sigf(misc[3648 + 1056 + v]);
        float c2 = fv * c1 + iv * gv;
        float hh = ov * tanhf(c2);
        h2f[v] = hh;
        if (bid == 0) { misc[1536 + v] = hh; misc[1888 + v] = c2; }
    }
    __syncthreads();
    int j = bid * 128 + t;
    float a = bihf[j] + bhhf[j];
    const float* wh = whhf + (size_t)j * VEC;
    for (int k = 0; k < VEC; k += 4)
        a += wh[k] * h2f[k] + wh[k + 1] * h2f[k + 1] + wh[k + 2] * h2f[k + 2] + wh[k + 3] * h2f[k + 3];
    misc[5056 + j] = a;
}

// ---------------- W staging: 4 gates x 16 rows x 352 bf16 -> LDS (rows padded to 360, 46KB) ----------------
// Measured local optimum (72.7us). Occupancy-raising variants all regressed:
// 128q acc (r12: 102us), 2-pass 2-gate (r18: 91us), hybrid 2LDS+2global (r21: 81us).
__device__ __forceinline__ void stage_W(const unsigned short* __restrict__ Wb, int h0, int t,
                                        unsigned short (*Wlds)[16][360])
{
    for (int i = t; i < 2816; i += 256) {
        int gate = i / 704, rem = i - gate * 704;
        int row = rem / 44, ch = rem - row * 44;
        *(uint4*)&Wlds[gate][row][ch * 8] =
            *(const uint4*)(Wb + ((size_t)gate * HID + h0 + row) * VEC + ch * 8);
    }
}

// GEMM core reading W from LDS: 4 global X loads + 4 LDS W reads -> 16 MFMA per K-step.
__device__ __forceinline__ void lstm_gemm_lds(
    const unsigned short* __restrict__ Xb,
    const unsigned short (*Wlds)[16][360],
    int q0, int li, int grp, int Q, float4v acc[4][4])
{
    const unsigned short* xp[4];
#pragma unroll
    for (int mf = 0; mf < 4; ++mf) {
        int qr = q0 + mf * 16 + li;
        if (qr > Q - 1) qr = Q - 1;
        xp[mf] = Xb + (size_t)qr * VEC + grp * 8;
    }
#pragma unroll
    for (int gi = 0; gi < 4; ++gi)
#pragma unroll
        for (int mf = 0; mf < 4; ++mf) acc[gi][mf] = (float4v){0.f, 0.f, 0.f, 0.f};
#pragma unroll 2
    for (int ks = 0; ks < 11; ++ks) {
        int ko = ks * 32;
        short8v a0 = *(const short8v*)(xp[0] + ko);
        short8v a1 = *(const short8v*)(xp[1] + ko);
        short8v a2 = *(const short8v*)(xp[2] + ko);
        short8v a3 = *(const short8v*)(xp[3] + ko);
        short8v b0 = *(const short8v*)&Wlds[0][li][ko + grp * 8];
        short8v b1 = *(const short8v*)&Wlds[1][li][ko + grp * 8];
        short8v b2 = *(const short8v*)&Wlds[2][li][ko + grp * 8];
        short8v b3 = *(const short8v*)&Wlds[3][li][ko + grp * 8];
        acc[0][0] = __builtin_amdgcn_mfma_f32_16x16x32_bf16(a0, b0, acc[0][0], 0, 0, 0);
        acc[0][1] = __builtin_amdgcn_mfma_f32_16x16x32_bf16(a1, b0, acc[0][1], 0, 0, 0);
        acc[0][2] = __builtin_amdgcn_mfma_f32_16x16x32_bf16(a2, b0, acc[0][2], 0, 0, 0);
        acc[0][3] = __builtin_amdgcn_mfma_f32_16x16x32_bf16(a3, b0, acc[0][3], 0, 0, 0);
        acc[1][0] = __builtin_amdgcn_mfma_f32_16x16x32_bf16(a0, b1, acc[1][0], 0, 0, 0);
        acc[1][1] = __builtin_amdgcn_mfma_f32_16x16x32_bf16(a1, b1, acc[1][1], 0, 0, 0);
        acc[1][2] = __builtin_amdgcn_mfma_f32_16x16x32_bf16(a2, b1, acc[1][2], 0, 0, 0);
        acc[1][3] = __builtin_amdgcn_mfma_f32_16x16x32_bf16(a3, b1, acc[1][3], 0, 0, 0);
        acc[2][0] = __builtin_amdgcn_mfma_f32_16x16x32_bf16(a0, b2, acc[2][0], 0, 0, 0);
        acc[2][1] = __builtin_amdgcn_mfma_f32_16x16x32_bf16(a1, b2, acc[2][1], 0, 0, 0);
        acc[2][2] = __builtin_amdgcn_mfma_f32_16x16x32_bf16(a2, b2, acc[2][2], 0, 0, 0);
        acc[2][3] = __builtin_amdgcn_mfma_f32_16x16x32_bf16(a3, b2, acc[2][3], 0, 0, 0);
        acc[3][0] = __builtin_amdgcn_mfma_f32_16x16x32_bf16(a0, b3, acc[3][0], 0, 0, 0);
        acc[3][1] = __builtin_amdgcn_mfma_f32_16x16x32_bf16(a1, b3, acc[3][1], 0, 0, 0);
        acc[3][2] = __builtin_amdgcn_mfma_f32_16x16x32_bf16(a2, b3, acc[3][2], 0, 0, 0);
        acc[3][3] = __builtin_amdgcn_mfma_f32_16x16x32_bf16(a3, b3, acc[3][3], 0, 0, 0);
    }
}

// ---------------- dual first-step kernel: y<22 -> fwd step2 (Wf), y>=22 -> bwd step0 (Wr) ----------------
__global__ __launch_bounds__(256, 4) void lstm_dual(
    const unsigned short* __restrict__ zq,
    const unsigned short* __restrict__ Wf, const unsigned short* __restrict__ Wr,
    const float* __restrict__ misc, const float* __restrict__ bihr, const float* __restrict__ bhhr,
    unsigned short* __restrict__ h3fb, unsigned short* __restrict__ hb1b,
    unsigned short* __restrict__ cb1b, int Q)
{
    __shared__ unsigned short Wlds[4][16][360];
    int t = threadIdx.x, wv = t >> 6, lane = t & 63;
    int li = lane & 15, grp = lane >> 4;
    int q0 = blockIdx.x * 256 + wv * 64;
    int fwd = (blockIdx.y < 22);
    int h0 = (fwd ? blockIdx.y : blockIdx.y - 22) * 16;
    int h = h0 + li;
    stage_W(fwd ? Wf : Wr, h0, t, Wlds);
    __syncthreads();
    float4v acc[4][4];
    lstm_gemm_lds(zq, Wlds, q0, li, grp, Q, acc);
    if (fwd) {
        float ai = misc[5056 + h], afv = misc[5056 + HID + h];
        float ag = misc[5056 + 2 * HID + h], ao = misc[5056 + 3 * HID + h];
        float cc1 = misc[1888 + h];
#pragma unroll
        for (int mf = 0; mf < 4; ++mf)
#pragma unroll
            for (int r = 0; r < 4; ++r) {
                int q = q0 + mf * 16 + grp * 4 + r;
                if (q >= Q) continue;
                float iv = sigf(acc[0][mf][r] + ai);
                float fv = sigf(acc[1][mf][r] + afv);
                float gv = ftanh(acc[2][mf][r] + ag);
                float ov = sigf(acc[3][mf][r] + ao);
                float cn = fmaf(fv, cc1, iv * gv);
                h3fb[(size_t)q * HID + h] = f2bf(ov * ftanh(cn));
            }
    } else {
        float ai = bihr[h] + bhhr[h];
        float ag = bihr[2 * HID + h] + bhhr[2 * HID + h];
        float ao = bihr[3 * HID + h] + bhhr[3 * HID + h];
#pragma unroll
        for (int mf = 0; mf < 4; ++mf)
#pragma unroll
            for (int r = 0; r < 4; ++r) {
                int q = q0 + mf * 16 + grp * 4 + r;
                if (q >= Q) continue;
                float iv = sigf(acc[0][mf][r] + ai);
                float gv = ftanh(acc[2][mf][r] + ag);
                float ov = sigf(acc[3][mf][r] + ao);
                float cn = iv * gv;
                hb1b[(size_t)q * HID + h] = f2bf(ov * ftanh(cn));
                cb1b[(size_t)q * HID + h] = f2bf(cn);
            }
    }
}

// ---------------- recurrent LSTM step: gates = hprev@Wh + add1 ; cprev bf16 per-q ----------------
__global__ __launch_bounds__(256, 4) void lstm_mfma(
    const unsigned short* __restrict__ Xb, const unsigned short* __restrict__ Wb,
    const float* __restrict__ add1, const unsigned short* __restrict__ cprevb,
    unsigned short* __restrict__ hbf, unsigned short* __restrict__ cbf, int Q)
{
    __shared__ unsigned short Wlds[4][16][360];
    int t = threadIdx.x, wv = t >> 6, lane = t & 63;
    int li = lane & 15, grp = lane >> 4;
    int q0 = blockIdx.x * 256 + wv * 64;
    int h0 = blockIdx.y * 16;
    int h = h0 + li;
    stage_W(Wb, h0, t, Wlds);
    __syncthreads();
    float4v acc[4][4];
    lstm_gemm_lds(Xb, Wlds, q0, li, grp, Q, acc);
    float ai = add1[h], afv = add1[HID + h], ag = add1[2 * HID + h], ao = add1[3 * HID + h];
#pragma unroll
    for (int mf = 0; mf < 4; ++mf) {
#pragma unroll
        for (int r = 0; r < 4; ++r) {
            int q = q0 + mf * 16 + grp * 4 + r;
            if (q >= Q) continue;
            float iv = sigf(acc[0][mf][r] + ai);
            float fv = sigf(acc[1][mf][r] + afv);
            float gv = ftanh(acc[2][mf][r] + ag);
            float ov = sigf(acc[3][mf][r] + ao);
            float cp = bf2f(cprevb[(size_t)q * HID + h]);
            float cn = fmaf(fv, cp, iv * gv);
            float hn = ov * ftanh(cn);
            hbf[(size_t)q * HID + h] = f2bf(hn);
            if (cbf) cbf[(size_t)q * HID + h] = f2bf(cn);
        }
    }
}

// ---------------- cosine sims + softmax; one wave per query (bf16 h inputs) ----------------
__global__ __launch_bounds__(256) void final_sims(
    const unsigned short* __restrict__ h3f, const unsigned short* __restrict__ hb1,
    const unsigned short* __restrict__ hb2, const unsigned short* __restrict__ hb3,
    const float* __restrict__ misc, float* __restrict__ out, int Q)
{
    int t = threadIdx.x;
    int wave = t >> 6, lane = t & 63;
    int q = blockIdx.x * 4 + wave;
    if (q >= Q) return;
    const unsigned short* a3 = h3f + (size_t)q * HID;
    const unsigned short* b1 = hb1 + (size_t)q * HID;
    const unsigned short* b2 = hb2 + (size_t)q * HID;
    const unsigned short* b3 = hb3 + (size_t)q * HID;
    const float* h1c = misc + 832;
    const float* h2c = misc + 1536;
    float sA = 0, sB = 0, s3 = 0, s4 = 0, s5 = 0, s6 = 0, s7 = 0, s8 = 0, s9 = 0, s10 = 0;
    for (int hh = lane; hh < HID; hh += 64) {
        float a = bf2f(a3[hh]), b = bf2f(b1[hh]), v2 = bf2f(b2[hh]), v3 = bf2f(b3[hh]);
        float u1 = h1c[hh], u2 = h2c[hh];
        sA += u1 * a;  sB += u2 * a;
        s3 += a * a;   s4 += b * b;
        s5 += v3 * b;  s6 += v2 * b;
        s7 += v3 * v3; s8 += v2 * v2;
        s9 += u1 * u1; s10 += u2 * u2;
    }
#pragma unroll
    for (int off = 32; off > 0; off >>= 1) {
        sA += __shfl_xor(sA, off);  sB += __shfl_xor(sB, off);
        s3 += __shfl_xor(s3, off);  s4 += __shfl_xor(s4, off);
        s5 += __shfl_xor(s5, off);  s6 += __shfl_xor(s6, off);
        s7 += __shfl_xor(s7, off);  s8 += __shfl_xor(s8, off);
        s9 += __shfl_xor(s9, off);  s10 += __shfl_xor(s10, off);
    }
    if (lane == 0) {
        float nq  = fmaxf(sqrtf(s3 + s4), 1e-8f);
        float ns0 = fmaxf(sqrtf(s9 + s7), 1e-8f);
        float ns1 = fmaxf(sqrtf(s10 + s8), 1e-8f);
        float sim0 = (sA + s5) / (ns0 * nq);
        float sim1 = (sB + s6) / (ns1 * nq);
        float mx = fmaxf(sim0, sim1);
        float e0 = __expf(sim0 - mx), e1 = __expf(sim1 - mx);
        float inv = 1.f / (e0 + e1);
        out[(size_t)q * 2 + 0] = e0 * inv;
        out[(size_t)q * 2 + 1] = e1 * inv;
    }
}

extern "C" void kernel_launch(void* const* d_in, const int* in_sizes, int n_in,
                              void* d_out, int out_size, void* d_ws, size_t ws_size,
                              hipStream_t stream)
{
    const float* x    = (const float*)d_in[0];
    const float* c1w  = (const float*)d_in[1];
    const float* c1b  = (const float*)d_in[2];
    const float* bn1g = (const float*)d_in[3];
    const float* bn1b = (const float*)d_in[4];
    const float* c2w  = (const float*)d_in[5];
    const float* c2b  = (const float*)d_in[6];
    const float* bn2g = (const float*)d_in[7];
    const float* bn2b = (const float*)d_in[8];
    const float* wihf = (const float*)d_in[9];
    const float* whhf = (const float*)d_in[10];
    const float* bihf = (const float*)d_in[11];
    const float* bhhf = (const float*)d_in[12];
    const float* wihr = (const float*)d_in[13];
    const float* whhr = (const float*)d_in[14];
    const float* bihr = (const float*)d_in[15];
    const float* bhhr = (const float*)d_in[16];

    int N = in_sizes[0] / LIN;
    int Q = N - NSUP;

    char* ws = (char*)d_ws;
    float* acc1  = (float*)(ws + 0);                       // 64 f32 stats accumulators (conv1)
    float* acc2  = (float*)(ws + 256);                     // 64 f32 stats accumulators (conv2)
    float* misc  = (float*)(ws + 1048576);                 // ~10.7K f32
    unsigned short* w2t = (unsigned short*)(ws + 1114112); // 5120 bf16
    unsigned short* Wf  = (unsigned short*)(ws + 2097152); // 1408*352 bf16
    unsigned short* Wr  = (unsigned short*)(ws + 3145728);
    unsigned short* Wh  = (unsigned short*)(ws + 4194304);
    unsigned short* z   = (unsigned short*)(ws + 5242880); // N*352 bf16
    unsigned short* h1  = (unsigned short*)(ws + 17825792);// N*64*32 bf16 (dead after conv2)
    const size_t Sb = (size_t)Q * HID * sizeof(unsigned short);   // ~11.5MB
    unsigned short* h3fb = (unsigned short*)(ws + 17825792);      // over h1 (dead)
    unsigned short* hb1b = (unsigned short*)(ws + 17825792 + Sb);
    unsigned short* cb1b = (unsigned short*)(ws + 17825792 + 2 * Sb);
    unsigned short* hb2b = (unsigned short*)(ws + 17825792 + 3 * Sb);
    unsigned short* cb2b = (unsigned short*)(ws + 17825792 + 4 * Sb);
    unsigned short* hb3b = (unsigned short*)(ws + 17825792 + 5 * Sb);

    // 0. zero the stats accumulators (capture-safe async memset)
    hipMemsetAsync(acc1, 0, 512, stream);
    // 1. cast weights
    {
        int tot = 3 * GATES * VEC + 5120;
        cast_weights<<<(tot + 255) / 256, 256, 0, stream>>>(wihf, wihr, whhr, c2w, Wf, Wr, Wh, w2t);
    }
    // 2. conv1: stats (atomic) + pooled raw, boundary-specialized blocks
    conv1_pass1<<<NBLK, 256, 0, stream>>>(x, c1w, c1b, acc1, h1, N);
    // 3. conv2 fused: BN1 consts from acc1; stage h1+BN1+relu in LDS, one MFMA pass -> acc2 + raw z
    conv2_fused<<<NBLK, 256, 0, stream>>>(h1, w2t, c2b, acc1, (float)((long long)N * L1C),
                                          bn1g, bn1b, z, acc2, N);
    // 4. z BN2+relu in place (BN2 consts from acc2)
    {
        long long total = (long long)N * 44;
        z_pass2<<<(unsigned)((total + 255) / 256), 256, 0, stream>>>(z, acc2, (float)((long long)N * L2C),
                                                                     bn2g, bn2b, total);
    }
    // 5. support path (3 launches)
    sup_a<<<22, 128, 0, stream>>>(z, wihf, bihf, bhhf, wihr, bihr, bhhr, misc);
    sup_b<<<11, 128, 0, stream>>>(wihf, whhf, bihf, bhhf, misc);
    sup_c<<<11, 128, 0, stream>>>(whhf, bihf, bhhf, misc);
    // 6. big LSTM steps (bf16 h/c state), 64q per wave / 256q per block, W staged via LDS
    const unsigned short* zq = z + (size_t)NSUP * VEC;
    int gx = (Q + 255) / 256;
    lstm_dual<<<dim3(gx, 44), 256, 0, stream>>>(zq, Wf, Wr, misc, bihr, bhhr, h3fb, hb1b, cb1b, Q);
    lstm_mfma<<<dim3(gx, 22), 256, 0, stream>>>(hb1b, Wh, misc + 6464, cb1b, hb2b, cb2b, Q);
    lstm_mfma<<<dim3(gx, 22), 256, 0, stream>>>(hb2b, Wh, misc + 7872, cb2b, hb3b, nullptr, Q);
    // 7. sims + softmax
    final_sims<<<(Q + 3) / 4, 256, 0, stream>>>(h3fb, hb1b, hb2b, hb3b, misc, (float*)d_out, Q);
}

// Round 27
// 351.242 us; speedup vs baseline: 1.9878x; 1.0105x over previous
//
#include <hip/hip_runtime.h>
#include <hip/hip_bf16.h>

#define NSUP 20
#define VEC 352
#define HID 352
#define GATES 1408
#define LIN 300
#define L1C 298
#define P1 59
#define L2C 57
#define P2 11
#define NBLK 2048   // grid for grid-stride stats/apply kernels

typedef __attribute__((ext_vector_type(8))) short short8v;
typedef __attribute__((ext_vector_type(4))) float float4v;

__device__ __forceinline__ float sigf(float x) { return 1.0f / (1.0f + __expf(-x)); }
// fast tanh: saturates to +/-1 at extremes without NaN; ~1e-6 rel err vs tanhf
__device__ __forceinline__ float ftanh(float x) { return 2.f / (1.f + __expf(-2.f * x)) - 1.f; }

__device__ __forceinline__ unsigned short f2bf(float x) {
    union { float f; unsigned u; } v; v.f = x;
    unsigned r = v.u + 0x7fffu + ((v.u >> 16) & 1u);
    return (unsigned short)(r >> 16);
}
__device__ __forceinline__ float bf2f(unsigned short s) {
    union { unsigned u; float f; } v; v.u = ((unsigned)s) << 16; return v.f;
}

// ---------------- cast weights to bf16 (plain row-major copies) + w2 transpose ----------------
__global__ __launch_bounds__(256) void cast_weights(
    const float* __restrict__ wihf, const float* __restrict__ wihr,
    const float* __restrict__ whhr, const float* __restrict__ w2,
    unsigned short* __restrict__ Wf, unsigned short* __restrict__ Wr,
    unsigned short* __restrict__ Wh, unsigned short* __restrict__ w2t)
{
    const int NW = GATES * VEC;
    int i = blockIdx.x * 256 + threadIdx.x;
    if (i < NW) Wf[i] = f2bf(wihf[i]);
    else if (i < 2 * NW) Wr[i - NW] = f2bf(wihr[i - NW]);
    else if (i < 3 * NW) Wh[i - 2 * NW] = f2bf(whhr[i - 2 * NW]);
    else if (i < 3 * NW + 5120) {
        int j = i - 3 * NW;
        int kk = j >> 10, c = (j >> 5) & 31, ci = j & 31;
        w2t[j] = f2bf(w2[c * 160 + ci * 5 + kk]);
    }
}

// ---------------- conv1 block body, boundary checks specialized away for interior blocks ----------
// CLO: front pad possible (bb==0).  CHI: tail pad / short positions possible (bb==14).
template<bool CLO, bool CHI>
__device__ __forceinline__ void c1_block(const float* __restrict__ xr, int bb,
    const float* __restrict__ wr, float b, float& sum, float& sq,
    unsigned short* __restrict__ shrow, int c)
{
    float xv[28];
    int base = bb * 20 - 4;
#pragma unroll
    for (int v8 = 0; v8 < 7; ++v8) {
        int bs = base + v8 * 4;
        bool ok = true;
        if (CLO) ok = ok && (bs >= 0);
        if (CHI) ok = ok && (bs + 3 < LIN);
        if (ok) {
            float4 q4 = *(const float4*)(xr + bs);
            xv[v8 * 4 + 0] = q4.x; xv[v8 * 4 + 1] = q4.y;
            xv[v8 * 4 + 2] = q4.z; xv[v8 * 4 + 3] = q4.w;
        } else {
#pragma unroll
            for (int e = 0; e < 4; ++e) {
                int ix = bs + e;
                xv[v8 * 4 + e] = (ix >= 0 && ix < LIN) ? xr[ix] : 0.f;
            }
        }
    }
#pragma unroll
    for (int grp = 0; grp < 4; ++grp) {
        int lo = bb * 4 + grp;
        float m = -1e30f;
#pragma unroll
        for (int d5 = 0; d5 < 5; ++d5) {
            int dj = grp * 5 + d5;
            if (!CHI || (bb * 20 + dj) <= 297) {
                float y = b;
#pragma unroll
                for (int k = 0; k < 5; ++k) y = fmaf(wr[k], xv[dj + 3 + k], y);
                sum += y; sq = fmaf(y, y, sq);
                m = fmaxf(m, y);
            }
        }
        if (!CHI || lo <= 58) shrow[(1 + lo) * 32 + c] = f2bf(m);
    }
}

// ---------------- conv1: stats (atomic) + pooled raw max -> h1 (bf16 [n][64][32], row=l+1) --------
// bb is data-divergent across halves (half0: bb=it, half1: bb=8+it) so control stays uniform.
// Iterations 1-5 and 7 are fully check-free; 0 and 6 carry the boundary specializations.
// NO launch_bounds cap: live set ~90 VGPR; (256,8) cap -> scratch spill, 416us (r25). 96 VGPR free = 74.9us.
__global__ __launch_bounds__(256) void conv1_pass1(const float* __restrict__ x,
    const float* __restrict__ w, const float* __restrict__ bias,
    float* __restrict__ acc1, unsigned short* __restrict__ h1, int N)
{
    __shared__ unsigned short sh1[4][2048];
    __shared__ float redS[256], redQ[256];
    int t = threadIdx.x;
    int wv = t >> 6, lane = t & 63;
    int c = lane & 31, half = lane >> 5;
    float wr[5];
#pragma unroll
    for (int k = 0; k < 5; ++k) wr[k] = w[c * 5 + k];
    float b = bias[c];
    float sum = 0.f, sq = 0.f;
    int bb0 = half * 8;
    for (int n = blockIdx.x * 4 + wv; n < N; n += gridDim.x * 4) {
        const float* xr = x + (size_t)n * LIN;
        unsigned short* shrow = &sh1[wv][0];
        // it 0: half0 at bb=0 (front pad); half1 at bb=8 (checks pass harmlessly)
        c1_block<true, false>(xr, bb0 + 0, wr, b, sum, sq, shrow, c);
#pragma unroll
        for (int it = 1; it <= 5; ++it)
            c1_block<false, false>(xr, bb0 + it, wr, b, sum, sq, shrow, c);
        // it 6: half1 at bb=14 (tail pad + short positions); half0 at bb=6 (checks pass)
        c1_block<false, true>(xr, bb0 + 6, wr, b, sum, sq, shrow, c);
        // it 7: only half0 (bb=7)
        if (half == 0) c1_block<false, false>(xr, 7, wr, b, sum, sq, shrow, c);
        if (half == 0) shrow[c] = 0;
        else { shrow[60 * 32 + c] = 0; shrow[61 * 32 + c] = 0;
               shrow[62 * 32 + c] = 0; shrow[63 * 32 + c] = 0; }
        __builtin_amdgcn_sched_barrier(0);   // keep LDS writes before flush reads
        unsigned short* hr = h1 + (size_t)n * 2048;
#pragma unroll
        for (int i = 0; i < 4; ++i)
            *(uint4*)(hr + i * 512 + lane * 8) = *(const uint4*)&sh1[wv][i * 512 + lane * 8];
        __builtin_amdgcn_sched_barrier(0);   // flush reads before next-iter overwrites
    }
    redS[t] = sum; redQ[t] = sq;
    __syncthreads();
    if (t < 32) {
        float s = 0.f, q = 0.f;
#pragma unroll
        for (int m = 0; m < 8; ++m) { s += redS[m * 32 + t]; q += redQ[m * 32 + t]; }
        atomicAdd(&acc1[t], s);
        atomicAdd(&acc1[32 + t], q);
    }
}

// ---------------- conv2 FUSED v4: v3 + async-STAGE split (T14): prefetch sample n+stride's h1
// tile into registers before the MFMA phase, so the ~600cy global latency hides under compute.
__global__ __launch_bounds__(256) void conv2_fused(const unsigned short* __restrict__ h1,
    const unsigned short* __restrict__ w2t, const float* __restrict__ b2,
    const float* __restrict__ acc1, float count1,
    const float* __restrict__ g1, const float* __restrict__ b1n,
    unsigned short* __restrict__ z, float* __restrict__ acc2, int N)
{
    __shared__ unsigned short hbl[4][64][40];
    __shared__ unsigned short ytb[4][32][66];
    __shared__ float bcv[32], sc1[32], sh1v[32];
    __shared__ float redS[4][32], redQ[4][32];
    int t = threadIdx.x, wv = t >> 6, lane = t & 63;
    int li = lane & 15, grp = lane >> 4;
    if (t < 32) {
        bcv[t] = b2[t];
        double m = (double)acc1[t] / (double)count1;
        double v = (double)acc1[32 + t] / (double)count1 - m * m;
        float istd = (float)(1.0 / sqrt(v + 1e-5));
        float s = istd * g1[t];
        sc1[t] = s; sh1v[t] = b1n[t] - (float)m * s;
    }
    short8v af[5][2];
#pragma unroll
    for (int kk = 0; kk < 5; ++kk)
#pragma unroll
        for (int mf = 0; mf < 2; ++mf)
            af[kk][mf] = *(const short8v*)(w2t + ((kk * 32 + mf * 16 + li) * 32 + grp * 8));
    float bc[2][4];
#pragma unroll
    for (int mf = 0; mf < 2; ++mf)
#pragma unroll
        for (int r = 0; r < 4; ++r) bc[mf][r] = b2[mf * 16 + grp * 4 + r];
    float sum[2][4] = {}, sq[2][4] = {};
    __syncthreads();
    const int stride = gridDim.x * 4;
    int n = blockIdx.x * 4 + wv;
    uint4 cur[4];
    if (n < N) {
        const unsigned short* hb = h1 + (size_t)n * 2048;
#pragma unroll
        for (int i4 = 0; i4 < 4; ++i4) {
            int i = i4 * 64 + lane;
            cur[i4] = *(const uint4*)(hb + (i >> 2) * 32 + (i & 3) * 8);
        }
    }
    while (n < N) {
        int nn = n + stride;
        // stage current tile from regs: raw -> BN1 + relu (rows 1..59), pads -> 0
#pragma unroll
        for (int i4 = 0; i4 < 4; ++i4) {
            int i = i4 * 64 + lane;
            int row = i >> 2, ch0 = (i & 3) * 8;
            union { uint4 v; unsigned short u[8]; } d, o;
            d.v = cur[i4];
            if (row >= 1 && row <= 59) {
#pragma unroll
                for (int e = 0; e < 8; ++e) {
                    int c = ch0 + e;
                    float y = fmaf(sc1[c], bf2f(d.u[e]), sh1v[c]);
                    o.u[e] = f2bf(fmaxf(y, 0.f));
                }
            } else {
                o.v = (uint4){0u, 0u, 0u, 0u};
            }
            *(uint4*)&hbl[wv][row][ch0] = o.v;
        }
        __builtin_amdgcn_sched_barrier(0);
        // issue next-tile loads now; latency hides under the MFMA/pooling phase below
        if (nn < N) {
            const unsigned short* hb2 = h1 + (size_t)nn * 2048;
#pragma unroll
            for (int i4 = 0; i4 < 4; ++i4) {
                int i = i4 * 64 + lane;
                cur[i4] = *(const uint4*)(hb2 + (i >> 2) * 32 + (i & 3) * 8);
            }
        }
        __builtin_amdgcn_sched_barrier(0);
#pragma unroll
        for (int lt = 0; lt < 4; ++lt) {
            float4v acc0 = {0.f, 0.f, 0.f, 0.f}, acc1v = {0.f, 0.f, 0.f, 0.f};
#pragma unroll
            for (int kk = 0; kk < 5; ++kk) {
                int row = lt * 16 + li + kk; row = row > 63 ? 63 : row;
                short8v bf = *(const short8v*)&hbl[wv][row][grp * 8];
                acc0 = __builtin_amdgcn_mfma_f32_16x16x32_bf16(af[kk][0], bf, acc0, 0, 0, 0);
                acc1v = __builtin_amdgcn_mfma_f32_16x16x32_bf16(af[kk][1], bf, acc1v, 0, 0, 0);
            }
            if (lt * 16 + li < L2C) {
#pragma unroll
                for (int r = 0; r < 4; ++r) {
                    float y0 = acc0[r] + bc[0][r]; sum[0][r] += y0; sq[0][r] = fmaf(y0, y0, sq[0][r]);
                    float y1 = acc1v[r] + bc[1][r]; sum[1][r] += y1; sq[1][r] = fmaf(y1, y1, sq[1][r]);
                }
            }
#pragma unroll
            for (int r = 0; r < 4; ++r) {
                ytb[wv][grp * 4 + r][lt * 16 + li] = f2bf(acc0[r]);
                ytb[wv][16 + grp * 4 + r][lt * 16 + li] = f2bf(acc1v[r]);
            }
        }
        unsigned short* zr = z + (size_t)n * VEC;
        for (int s = lane; s < VEC; s += 64) {
            int c = s / 11, lo = s % 11;
            float m = bf2f(ytb[wv][c][lo * 5]);
#pragma unroll
            for (int d = 1; d < 5; ++d) m = fmaxf(m, bf2f(ytb[wv][c][lo * 5 + d]));
            zr[s] = f2bf(m + bcv[c]);          // raw pooled + bias; BN2+relu in z_pass2
        }
        __builtin_amdgcn_sched_barrier(0);
        n = nn;
    }
#pragma unroll
    for (int mf = 0; mf < 2; ++mf)
#pragma unroll
        for (int r = 0; r < 4; ++r) {
            float s = sum[mf][r], q = sq[mf][r];
#pragma unroll
            for (int m = 1; m < 16; m <<= 1) { s += __shfl_xor(s, m); q += __shfl_xor(q, m); }
            if (li == 0) { redS[wv][mf * 16 + grp * 4 + r] = s; redQ[wv][mf * 16 + grp * 4 + r] = q; }
        }
    __syncthreads();
    if (t < 32) atomicAdd(&acc2[t], redS[0][t] + redS[1][t] + redS[2][t] + redS[3][t]);
    else if (t < 64) atomicAdd(&acc2[t - 32 + 32], redQ[0][t - 32] + redQ[1][t - 32] + redQ[2][t - 32] + redQ[3][t - 32]);
}

// ---------------- z pass2: BN2 consts from acc2 in prologue; in-place BN2+relu on z ----------------
__global__ __launch_bounds__(256) void z_pass2(unsigned short* __restrict__ z,
    const float* __restrict__ acc2, float count2,
    const float* __restrict__ g2, const float* __restrict__ be2, long long total)
{
    __shared__ float sc[32], sh[32];
    int t = threadIdx.x;
    if (t < 32) {
        double m = (double)acc2[t] / (double)count2;
        double v = (double)acc2[32 + t] / (double)count2 - m * m;
        float istd = (float)(1.0 / sqrt(v + 1e-5));
        float s = istd * g2[t];
        sc[t] = s; sh[t] = be2[t] - (float)m * s;
    }
    __syncthreads();
    long long i = (long long)blockIdx.x * 256 + t;
    if (i >= total) return;
    long long n = i / 44; int r = (int)(i % 44);
    unsigned short* p = z + n * VEC + r * 8;
    union { uint4 v; unsigned short u[8]; } d;
    d.v = *(const uint4*)p;
#pragma unroll
    for (int e = 0; e < 8; ++e) {
        int c = (r * 8 + e) / 11;
        float y = fmaf(sc[c], bf2f(d.u[e]), sh[c]);
        d.u[e] = f2bf(fmaxf(y, 0.f));
    }
    *(uint4*)p = d.v;
}

// ---------------- support path (3 launches) ----------------
__global__ __launch_bounds__(128) void sup_a(const unsigned short* __restrict__ z,
    const float* __restrict__ wihf, const float* __restrict__ bihf, const float* __restrict__ bhhf,
    const float* __restrict__ wihr, const float* __restrict__ bihr, const float* __restrict__ bhhr,
    float* __restrict__ misc)
{
    __shared__ float s0[VEC], s1[VEC];
    int t = threadIdx.x, bid = blockIdx.x;
    for (int v = t; v < VEC; v += 128) {
        float a0 = 0.f, a1 = 0.f;
        for (int k = 0; k < 10; ++k) {
            a0 += bf2f(z[(size_t)k * VEC + v]);
            a1 += bf2f(z[(size_t)(10 + k) * VEC + v]);
        }
        s0[v] = a0 * 0.1f; s1[v] = a1 * 0.1f;
    }
    __syncthreads();
    if (bid == 0)
        for (int v = t; v < VEC; v += 128) { misc[128 + v] = s0[v]; misc[480 + v] = s1[v]; }
    if (bid < 11) {
        int j = bid * 128 + t;
        float a = bihf[j] + bhhf[j];
        const float* w = wihf + (size_t)j * VEC;
        for (int k = 0; k < VEC; k += 4)
            a += w[k] * s0[k] + w[k + 1] * s0[k + 1] + w[k + 2] * s0[k + 2] + w[k + 3] * s0[k + 3];
        misc[2240 + j] = a;
    } else {
        int j = (bid - 11) * 128 + t;
        float br = bihr[j] + bhhr[j];
        const float* wr = wihr + (size_t)j * VEC;
        float p1 = br, p0 = br;
        for (int k = 0; k < VEC; k += 4) {
            p1 += wr[k] * s1[k] + wr[k + 1] * s1[k + 1] + wr[k + 2] * s1[k + 2] + wr[k + 3] * s1[k + 3];
            p0 += wr[k] * s0[k] + wr[k + 1] * s0[k + 1] + wr[k + 2] * s0[k + 2] + wr[k + 3] * s0[k + 3];
        }
        misc[6464 + j] = p1;
        misc[7872 + j] = p0;
    }
}

// sup_b: local cell0 -> h1f; mode1 gates; block 0 persists h1f
__global__ __launch_bounds__(128) void sup_b(
    const float* __restrict__ wihf, const float* __restrict__ whhf,
    const float* __restrict__ bihf, const float* __restrict__ bhhf, float* __restrict__ misc)
{
    __shared__ float s1[VEC], h1f[VEC];
    int t = threadIdx.x, bid = blockIdx.x;
    for (int v = t; v < VEC; v += 128) {
        s1[v] = misc[480 + v];
        float iv = sigf(misc[2240 + v]);
        float gv = tanhf(misc[2240 + 704 + v]);
        float ov = sigf(misc[2240 + 1056 + v]);
        h1f[v] = ov * tanhf(iv * gv);
    }
    __syncthreads();
    if (bid == 0)
        for (int v = t; v < VEC; v += 128) misc[832 + v] = h1f[v];
    int j = bid * 128 + t;
    float a = bihf[j] + bhhf[j];
    const float* w = wihf + (size_t)j * VEC;
    const float* wh = whhf + (size_t)j * VEC;
    for (int k = 0; k < VEC; k += 4) {
        a += w[k] * s1[k] + w[k + 1] * s1[k + 1] + w[k + 2] * s1[k + 2] + w[k + 3] * s1[k + 3];
        a += wh[k] * h1f[k] + wh[k + 1] * h1f[k + 1] + wh[k + 2] * h1f[k + 2] + wh[k + 3] * h1f[k + 3];
    }
    misc[3648 + j] = a;
}

// sup_c: local cell0 (c1) + cell1 -> h2f/c2f; gf_const gates; block 0 persists h2f/c2f
__global__ __launch_bounds__(128) void sup_c(
    const float* __restrict__ whhf, const float* __restrict__ bihf,
    const float* __restrict__ bhhf, float* __restrict__ misc)
{
    __shared__ float h2f[VEC];
    int t = threadIdx.x, bid = blockIdx.x;
    for (int v = t; v < VEC; v += 128) {
        float iv0 = sigf(misc[2240 + v]);
        float gv0 = tanhf(misc[2240 + 704 + v]);
        float c1 = iv0 * gv0;
        float iv = sigf(misc[3648 + v]);
        float fv = sigf(misc[3648 + 352 + v]);
        float gv = tanhf(misc[3648 + 704 + v]);
        float ov = sigf(misc[3648 + 1056 + v]);
        float c2 = fv * c1 + iv * gv;
        float hh = ov * tanhf(c2);
        h2f[v] = hh;
        if (bid == 0) { misc[1536 + v] = hh; misc[1888 + v] = c2; }
    }
    __syncthreads();
    int j = bid * 128 + t;
    float a = bihf[j] + bhhf[j];
    const float* wh = whhf + (size_t)j * VEC;
    for (int k = 0; k < VEC; k += 4)
        a += wh[k] * h2f[k] + wh[k + 1] * h2f[k + 1] + wh[k + 2] * h2f[k + 2] + wh[k + 3] * h2f[k + 3];
    misc[5056 + j] = a;
}

// ---------------- W staging: 4 gates x 16 rows x 352 bf16 -> LDS (rows padded to 360, 46KB) ----------------
// Measured local optimum (72.7us). Occupancy-raising variants all regressed:
// 128q acc (r12: 102us), 2-pass 2-gate (r18: 91us), hybrid 2LDS+2global (r21: 81us).
__device__ __forceinline__ void stage_W(const unsigned short* __restrict__ Wb, int h0, int t,
                                        unsigned short (*Wlds)[16][360])
{
    for (int i = t; i < 2816; i += 256) {
        int gate = i / 704, rem = i - gate * 704;
        int row = rem / 44, ch = rem - row * 44;
        *(uint4*)&Wlds[gate][row][ch * 8] =
            *(const uint4*)(Wb + ((size_t)gate * HID + h0 + row) * VEC + ch * 8);
    }
}

// GEMM core reading W from LDS: 4 global X loads + 4 LDS W reads -> 16 MFMA per K-step.
// setprio(1) around the MFMA loop (T5): waves are phase-diverse after stage_W's single barrier,
// so the CU scheduler can favor MFMA-entering waves over epilogue/transcendental waves.
__device__ __forceinline__ void lstm_gemm_lds(
    const unsigned short* __restrict__ Xb,
    const unsigned short (*Wlds)[16][360],
    int q0, int li, int grp, int Q, float4v acc[4][4])
{
    const unsigned short* xp[4];
#pragma unroll
    for (int mf = 0; mf < 4; ++mf) {
        int qr = q0 + mf * 16 + li;
        if (qr > Q - 1) qr = Q - 1;
        xp[mf] = Xb + (size_t)qr * VEC + grp * 8;
    }
#pragma unroll
    for (int gi = 0; gi < 4; ++gi)
#pragma unroll
        for (int mf = 0; mf < 4; ++mf) acc[gi][mf] = (float4v){0.f, 0.f, 0.f, 0.f};
    __builtin_amdgcn_s_setprio(1);
#pragma unroll 2
    for (int ks = 0; ks < 11; ++ks) {
        int ko = ks * 32;
        short8v a0 = *(const short8v*)(xp[0] + ko);
        short8v a1 = *(const short8v*)(xp[1] + ko);
        short8v a2 = *(const short8v*)(xp[2] + ko);
        short8v a3 = *(const short8v*)(xp[3] + ko);
        short8v b0 = *(const short8v*)&Wlds[0][li][ko + grp * 8];
        short8v b1 = *(const short8v*)&Wlds[1][li][ko + grp * 8];
        short8v b2 = *(const short8v*)&Wlds[2][li][ko + grp * 8];
        short8v b3 = *(const short8v*)&Wlds[3][li][ko + grp * 8];
        acc[0][0] = __builtin_amdgcn_mfma_f32_16x16x32_bf16(a0, b0, acc[0][0], 0, 0, 0);
        acc[0][1] = __builtin_amdgcn_mfma_f32_16x16x32_bf16(a1, b0, acc[0][1], 0, 0, 0);
        acc[0][2] = __builtin_amdgcn_mfma_f32_16x16x32_bf16(a2, b0, acc[0][2], 0, 0, 0);
        acc[0][3] = __builtin_amdgcn_mfma_f32_16x16x32_bf16(a3, b0, acc[0][3], 0, 0, 0);
        acc[1][0] = __builtin_amdgcn_mfma_f32_16x16x32_bf16(a0, b1, acc[1][0], 0, 0, 0);
        acc[1][1] = __builtin_amdgcn_mfma_f32_16x16x32_bf16(a1, b1, acc[1][1], 0, 0, 0);
        acc[1][2] = __builtin_amdgcn_mfma_f32_16x16x32_bf16(a2, b1, acc[1][2], 0, 0, 0);
        acc[1][3] = __builtin_amdgcn_mfma_f32_16x16x32_bf16(a3, b1, acc[1][3], 0, 0, 0);
        acc[2][0] = __builtin_amdgcn_mfma_f32_16x16x32_bf16(a0, b2, acc[2][0], 0, 0, 0);
        acc[2][1] = __builtin_amdgcn_mfma_f32_16x16x32_bf16(a1, b2, acc[2][1], 0, 0, 0);
        acc[2][2] = __builtin_amdgcn_mfma_f32_16x16x32_bf16(a2, b2, acc[2][2], 0, 0, 0);
        acc[2][3] = __builtin_amdgcn_mfma_f32_16x16x32_bf16(a3, b2, acc[2][3], 0, 0, 0);
        acc[3][0] = __builtin_amdgcn_mfma_f32_16x16x32_bf16(a0, b3, acc[3][0], 0, 0, 0);
        acc[3][1] = __builtin_amdgcn_mfma_f32_16x16x32_bf16(a1, b3, acc[3][1], 0, 0, 0);
        acc[3][2] = __builtin_amdgcn_mfma_f32_16x16x32_bf16(a2, b3, acc[3][2], 0, 0, 0);
        acc[3][3] = __builtin_amdgcn_mfma_f32_16x16x32_bf16(a3, b3, acc[3][3], 0, 0, 0);
    }
    __builtin_amdgcn_s_setprio(0);
}

// ---------------- dual first-step kernel: y<22 -> fwd step2 (Wf), y>=22 -> bwd step0 (Wr) ----------------
__global__ __launch_bounds__(256, 4) void lstm_dual(
    const unsigned short* __restrict__ zq,
    const unsigned short* __restrict__ Wf, const unsigned short* __restrict__ Wr,
    const float* __restrict__ misc, const float* __restrict__ bihr, const float* __restrict__ bhhr,
    unsigned short* __restrict__ h3fb, unsigned short* __restrict__ hb1b,
    unsigned short* __restrict__ cb1b, int Q)
{
    __shared__ unsigned short Wlds[4][16][360];
    int t = threadIdx.x, wv = t >> 6, lane = t & 63;
    int li = lane & 15, grp = lane >> 4;
    int q0 = blockIdx.x * 256 + wv * 64;
    int fwd = (blockIdx.y < 22);
    int h0 = (fwd ? blockIdx.y : blockIdx.y - 22) * 16;
    int h = h0 + li;
    stage_W(fwd ? Wf : Wr, h0, t, Wlds);
    __syncthreads();
    float4v acc[4][4];
    lstm_gemm_lds(zq, Wlds, q0, li, grp, Q, acc);
    if (fwd) {
        float ai = misc[5056 + h], afv = misc[5056 + HID + h];
        float ag = misc[5056 + 2 * HID + h], ao = misc[5056 + 3 * HID + h];
        float cc1 = misc[1888 + h];
#pragma unroll
        for (int mf = 0; mf < 4; ++mf)
#pragma unroll
            for (int r = 0; r < 4; ++r) {
                int q = q0 + mf * 16 + grp * 4 + r;
                if (q >= Q) continue;
                float iv = sigf(acc[0][mf][r] + ai);
                float fv = sigf(acc[1][mf][r] + afv);
                float gv = ftanh(acc[2][mf][r] + ag);
                float ov = sigf(acc[3][mf][r] + ao);
                float cn = fmaf(fv, cc1, iv * gv);
                h3fb[(size_t)q * HID + h] = f2bf(ov * ftanh(cn));
            }
    } else {
        float ai = bihr[h] + bhhr[h];
        float ag = bihr[2 * HID + h] + bhhr[2 * HID + h];
        float ao = bihr[3 * HID + h] + bhhr[3 * HID + h];
#pragma unroll
        for (int mf = 0; mf < 4; ++mf)
#pragma unroll
            for (int r = 0; r < 4; ++r) {
                int q = q0 + mf * 16 + grp * 4 + r;
                if (q >= Q) continue;
                float iv = sigf(acc[0][mf][r] + ai);
                float gv = ftanh(acc[2][mf][r] + ag);
                float ov = sigf(acc[3][mf][r] + ao);
                float cn = iv * gv;
                hb1b[(size_t)q * HID + h] = f2bf(ov * ftanh(cn));
                cb1b[(size_t)q * HID + h] = f2bf(cn);
            }
    }
}

// ---------------- recurrent LSTM step: gates = hprev@Wh + add1 ; cprev bf16 per-q ----------------
__global__ __launch_bounds__(256, 4) void lstm_mfma(
    const unsigned short* __restrict__ Xb, const unsigned short* __restrict__ Wb,
    const float* __restrict__ add1, const unsigned short* __restrict__ cprevb,
    unsigned short* __restrict__ hbf, unsigned short* __restrict__ cbf, int Q)
{
    __shared__ unsigned short Wlds[4][16][360];
    int t = threadIdx.x, wv = t >> 6, lane = t & 63;
    int li = lane & 15, grp = lane >> 4;
    int q0 = blockIdx.x * 256 + wv * 64;
    int h0 = blockIdx.y * 16;
    int h = h0 + li;
    stage_W(Wb, h0, t, Wlds);
    __syncthreads();
    float4v acc[4][4];
    lstm_gemm_lds(Xb, Wlds, q0, li, grp, Q, acc);
    float ai = add1[h], afv = add1[HID + h], ag = add1[2 * HID + h], ao = add1[3 * HID + h];
#pragma unroll
    for (int mf = 0; mf < 4; ++mf) {
#pragma unroll
        for (int r = 0; r < 4; ++r) {
            int q = q0 + mf * 16 + grp * 4 + r;
            if (q >= Q) continue;
            float iv = sigf(acc[0][mf][r] + ai);
            float fv = sigf(acc[1][mf][r] + afv);
            float gv = ftanh(acc[2][mf][r] + ag);
            float ov = sigf(acc[3][mf][r] + ao);
            float cp = bf2f(cprevb[(size_t)q * HID + h]);
            float cn = fmaf(fv, cp, iv * gv);
            float hn = ov * ftanh(cn);
            hbf[(size_t)q * HID + h] = f2bf(hn);
            if (cbf) cbf[(size_t)q * HID + h] = f2bf(cn);
        }
    }
}

// ---------------- cosine sims + softmax; one wave per query (bf16 h inputs) ----------------
__global__ __launch_bounds__(256) void final_sims(
    const unsigned short* __restrict__ h3f, const unsigned short* __restrict__ hb1,
    const unsigned short* __restrict__ hb2, const unsigned short* __restrict__ hb3,
    const float* __restrict__ misc, float* __restrict__ out, int Q)
{
    int t = threadIdx.x;
    int wave = t >> 6, lane = t & 63;
    int q = blockIdx.x * 4 + wave;
    if (q >= Q) return;
    const unsigned short* a3 = h3f + (size_t)q * HID;
    const unsigned short* b1 = hb1 + (size_t)q * HID;
    const unsigned short* b2 = hb2 + (size_t)q * HID;
    const unsigned short* b3 = hb3 + (size_t)q * HID;
    const float* h1c = misc + 832;
    const float* h2c = misc + 1536;
    float sA = 0, sB = 0, s3 = 0, s4 = 0, s5 = 0, s6 = 0, s7 = 0, s8 = 0, s9 = 0, s10 = 0;
    for (int hh = lane; hh < HID; hh += 64) {
        float a = bf2f(a3[hh]), b = bf2f(b1[hh]), v2 = bf2f(b2[hh]), v3 = bf2f(b3[hh]);
        float u1 = h1c[hh], u2 = h2c[hh];
        sA += u1 * a;  sB += u2 * a;
        s3 += a * a;   s4 += b * b;
        s5 += v3 * b;  s6 += v2 * b;
        s7 += v3 * v3; s8 += v2 * v2;
        s9 += u1 * u1; s10 += u2 * u2;
    }
#pragma unroll
    for (int off = 32; off > 0; off >>= 1) {
        sA += __shfl_xor(sA, off);  sB += __shfl_xor(sB, off);
        s3 += __shfl_xor(s3, off);  s4 += __shfl_xor(s4, off);
        s5 += __shfl_xor(s5, off);  s6 += __shfl_xor(s6, off);
        s7 += __shfl_xor(s7, off);  s8 += __shfl_xor(s8, off);
        s9 += __shfl_xor(s9, off);  s10 += __shfl_xor(s10, off);
    }
    if (lane == 0) {
        float nq  = fmaxf(sqrtf(s3 + s4), 1e-8f);
        float ns0 = fmaxf(sqrtf(s9 + s7), 1e-8f);
        float ns1 = fmaxf(sqrtf(s10 + s8), 1e-8f);
        float sim0 = (sA + s5) / (ns0 * nq);
        float sim1 = (sB + s6) / (ns1 * nq);
        float mx = fmaxf(sim0, sim1);
        float e0 = __expf(sim0 - mx), e1 = __expf(sim1 - mx);
        float inv = 1.f / (e0 + e1);
        out[(size_t)q * 2 + 0] = e0 * inv;
        out[(size_t)q * 2 + 1] = e1 * inv;
    }
}

extern "C" void kernel_launch(void* const* d_in, const int* in_sizes, int n_in,
                              void* d_out, int out_size, void* d_ws, size_t ws_size,
                              hipStream_t stream)
{
    const float* x    = (const float*)d_in[0];
    const float* c1w  = (const float*)d_in[1];
    const float* c1b  = (const float*)d_in[2];
    const float* bn1g = (const float*)d_in[3];
    const float* bn1b = (const float*)d_in[4];
    const float* c2w  = (const float*)d_in[5];
    const float* c2b  = (const float*)d_in[6];
    const float* bn2g = (const float*)d_in[7];
    const float* bn2b = (const float*)d_in[8];
    const float* wihf = (const float*)d_in[9];
    const float* whhf = (const float*)d_in[10];
    const float* bihf = (const float*)d_in[11];
    const float* bhhf = (const float*)d_in[12];
    const float* wihr = (const float*)d_in[13];
    const float* whhr = (const float*)d_in[14];
    const float* bihr = (const float*)d_in[15];
    const float* bhhr = (const float*)d_in[16];

    int N = in_sizes[0] / LIN;
    int Q = N - NSUP;

    char* ws = (char*)d_ws;
    float* acc1  = (float*)(ws + 0);                       // 64 f32 stats accumulators (conv1)
    float* acc2  = (float*)(ws + 256);                     // 64 f32 stats accumulators (conv2)
    float* misc  = (float*)(ws + 1048576);                 // ~10.7K f32
    unsigned short* w2t = (unsigned short*)(ws + 1114112); // 5120 bf16
    unsigned short* Wf  = (unsigned short*)(ws + 2097152); // 1408*352 bf16
    unsigned short* Wr  = (unsigned short*)(ws + 3145728);
    unsigned short* Wh  = (unsigned short*)(ws + 4194304);
    unsigned short* z   = (unsigned short*)(ws + 5242880); // N*352 bf16
    unsigned short* h1  = (unsigned short*)(ws + 17825792);// N*64*32 bf16 (dead after conv2)
    const size_t Sb = (size_t)Q * HID * sizeof(unsigned short);   // ~11.5MB
    unsigned short* h3fb = (unsigned short*)(ws + 17825792);      // over h1 (dead)
    unsigned short* hb1b = (unsigned short*)(ws + 17825792 + Sb);
    unsigned short* cb1b = (unsigned short*)(ws + 17825792 + 2 * Sb);
    unsigned short* hb2b = (unsigned short*)(ws + 17825792 + 3 * Sb);
    unsigned short* cb2b = (unsigned short*)(ws + 17825792 + 4 * Sb);
    unsigned short* hb3b = (unsigned short*)(ws + 17825792 + 5 * Sb);

    // 0. zero the stats accumulators (capture-safe async memset)
    hipMemsetAsync(acc1, 0, 512, stream);
    // 1. cast weights
    {
        int tot = 3 * GATES * VEC + 5120;
        cast_weights<<<(tot + 255) / 256, 256, 0, stream>>>(wihf, wihr, whhr, c2w, Wf, Wr, Wh, w2t);
    }
    // 2. conv1: stats (atomic) + pooled raw, boundary-specialized blocks
    conv1_pass1<<<NBLK, 256, 0, stream>>>(x, c1w, c1b, acc1, h1, N);
    // 3. conv2 fused v4: BN1 consts from acc1; reg-prefetch next tile; one MFMA pass -> acc2 + raw z
    conv2_fused<<<NBLK, 256, 0, stream>>>(h1, w2t, c2b, acc1, (float)((long long)N * L1C),
                                          bn1g, bn1b, z, acc2, N);
    // 4. z BN2+relu in place (BN2 consts from acc2)
    {
        long long total = (long long)N * 44;
        z_pass2<<<(unsigned)((total + 255) / 256), 256, 0, stream>>>(z, acc2, (float)((long long)N * L2C),
                                                                     bn2g, bn2b, total);
    }
    // 5. support path (3 launches)
    sup_a<<<22, 128, 0, stream>>>(z, wihf, bihf, bhhf, wihr, bihr, bhhr, misc);
    sup_b<<<11, 128, 0, stream>>>(wihf, whhf, bihf, bhhf, misc);
    sup_c<<<11, 128, 0, stream>>>(whhf, bihf, bhhf, misc);
    // 6. big LSTM steps (bf16 h/c state), 64q per wave / 256q per block, W staged via LDS + setprio
    const unsigned short* zq = z + (size_t)NSUP * VEC;
    int gx = (Q + 255) / 256;
    lstm_dual<<<dim3(gx, 44), 256, 0, stream>>>(zq, Wf, Wr, misc, bihr, bhhr, h3fb, hb1b, cb1b, Q);
    lstm_mfma<<<dim3(gx, 22), 256, 0, stream>>>(hb1b, Wh, misc + 6464, cb1b, hb2b, cb2b, Q);
    lstm_mfma<<<dim3(gx, 22), 256, 0, stream>>>(hb2b, Wh, misc + 7872, cb2b, hb3b, nullptr, Q);
    // 7. sims + softmax
    final_sims<<<(Q + 3) / 4, 256, 0, stream>>>(h3fb, hb1b, hb2b, hb3b, misc, (float*)d_out, Q);
}

// Round 28
// 346.453 us; speedup vs baseline: 2.0152x; 1.0138x over previous
//
#include <hip/hip_runtime.h>
#include <hip/hip_bf16.h>

#define NSUP 20
#define VEC 352
#define HID 352
#define GATES 1408
#define LIN 300
#define L1C 298
#define P1 59
#define L2C 57
#define P2 11
#define NBLK 2048   // grid for grid-stride stats/apply kernels

typedef __attribute__((ext_vector_type(8))) short short8v;
typedef __attribute__((ext_vector_type(4))) float float4v;

__device__ __forceinline__ float sigf(float x) { return 1.0f / (1.0f + __expf(-x)); }
// fast tanh: saturates to +/-1 at extremes without NaN; ~1e-6 rel err vs tanhf
__device__ __forceinline__ float ftanh(float x) { return 2.f / (1.f + __expf(-2.f * x)) - 1.f; }

__device__ __forceinline__ unsigned short f2bf(float x) {
    union { float f; unsigned u; } v; v.f = x;
    unsigned r = v.u + 0x7fffu + ((v.u >> 16) & 1u);
    return (unsigned short)(r >> 16);
}
__device__ __forceinline__ float bf2f(unsigned short s) {
    union { unsigned u; float f; } v; v.u = ((unsigned)s) << 16; return v.f;
}

// ---------------- cast weights to bf16 (plain row-major copies) + w2 transpose ----------------
__global__ __launch_bounds__(256) void cast_weights(
    const float* __restrict__ wihf, const float* __restrict__ wihr,
    const float* __restrict__ whhr, const float* __restrict__ w2,
    unsigned short* __restrict__ Wf, unsigned short* __restrict__ Wr,
    unsigned short* __restrict__ Wh, unsigned short* __restrict__ w2t)
{
    const int NW = GATES * VEC;
    int i = blockIdx.x * 256 + threadIdx.x;
    if (i < NW) Wf[i] = f2bf(wihf[i]);
    else if (i < 2 * NW) Wr[i - NW] = f2bf(wihr[i - NW]);
    else if (i < 3 * NW) Wh[i - 2 * NW] = f2bf(whhr[i - 2 * NW]);
    else if (i < 3 * NW + 5120) {
        int j = i - 3 * NW;
        int kk = j >> 10, c = (j >> 5) & 31, ci = j & 31;
        w2t[j] = f2bf(w2[c * 160 + ci * 5 + kk]);
    }
}

// ---------------- conv1 block body reading the x row from LDS (pads physically zero) ------------
// CHI: tail block (bb==14) - position count j<=297 and store lo<=58 checks only; loads unchecked.
template<bool CHI>
__device__ __forceinline__ void c1_block(const float* __restrict__ xsrow, int bb,
    const float* __restrict__ wr, float b, float& sum, float& sq,
    unsigned short* __restrict__ shrow, int c)
{
    float xv[28];
    int base = bb * 20;   // xs index: xs[i] = x[i-4], window for pos j: xs[j+3+k]
#pragma unroll
    for (int v8 = 0; v8 < 7; ++v8) {
        float4 q4 = *(const float4*)(xsrow + base + v8 * 4);
        xv[v8 * 4 + 0] = q4.x; xv[v8 * 4 + 1] = q4.y;
        xv[v8 * 4 + 2] = q4.z; xv[v8 * 4 + 3] = q4.w;
    }
#pragma unroll
    for (int grp = 0; grp < 4; ++grp) {
        int lo = bb * 4 + grp;
        float m = -1e30f;
#pragma unroll
        for (int d5 = 0; d5 < 5; ++d5) {
            int dj = grp * 5 + d5;
            if (!CHI || (bb * 20 + dj) <= 297) {
                float y = b;
#pragma unroll
                for (int k = 0; k < 5; ++k) y = fmaf(wr[k], xv[dj + 3 + k], y);
                sum += y; sq = fmaf(y, y, sq);
                m = fmaxf(m, y);
            }
        }
        if (!CHI || lo <= 58) shrow[(1 + lo) * 32 + c] = f2bf(m);
    }
}

// ---------------- conv1 v3: x row staged to LDS once per wave (cooperative, 2 load instrs/lane
// vs 105 redundant broadcast loads). Kills load-boundary checks (zero pads) and the deep
// global-load pipelining that forced 96 VGPR / 16% occupancy (r24-r26 ledger).
__global__ __launch_bounds__(256) void conv1_pass1(const float* __restrict__ x,
    const float* __restrict__ w, const float* __restrict__ bias,
    float* __restrict__ acc1, unsigned short* __restrict__ h1, int N)
{
    __shared__ float xs[4][308];            // [0..3]=0 pad, [4+i]=x[i], [304..307]=0 pad
    __shared__ unsigned short sh1[4][2048];
    __shared__ float redS[256], redQ[256];
    int t = threadIdx.x;
    int wv = t >> 6, lane = t & 63;
    int c = lane & 31, half = lane >> 5;
    if (lane < 4) { xs[wv][lane] = 0.f; xs[wv][304 + lane] = 0.f; }
    float wr[5];
#pragma unroll
    for (int k = 0; k < 5; ++k) wr[k] = w[c * 5 + k];
    float b = bias[c];
    float sum = 0.f, sq = 0.f;
    int bb0 = half * 8;
    for (int n = blockIdx.x * 4 + wv; n < N; n += gridDim.x * 4) {
        const float* xr = x + (size_t)n * LIN;
        // cooperative row stage: 75 float4 = 300 floats (lane 0..63 + lane 0..10 second round)
        float4 qa = *(const float4*)(xr + lane * 4);
        *(float4*)&xs[wv][4 + lane * 4] = qa;
        if (lane < 11) {
            float4 qb = *(const float4*)(xr + 256 + lane * 4);
            *(float4*)&xs[wv][4 + 256 + lane * 4] = qb;
        }
        __builtin_amdgcn_sched_barrier(0);   // xs writes before window reads
        const float* xsrow = &xs[wv][0];
        unsigned short* shrow = &sh1[wv][0];
        c1_block<false>(xsrow, bb0 + 0, wr, b, sum, sq, shrow, c);
#pragma unroll
        for (int it = 1; it <= 5; ++it)
            c1_block<false>(xsrow, bb0 + it, wr, b, sum, sq, shrow, c);
        // it 6: half1 at bb=14 (short positions); half0 at bb=6 (checks pass)
        c1_block<true>(xsrow, bb0 + 6, wr, b, sum, sq, shrow, c);
        // it 7: only half0 (bb=7)
        if (half == 0) c1_block<false>(xsrow, 7, wr, b, sum, sq, shrow, c);
        if (half == 0) shrow[c] = 0;
        else { shrow[60 * 32 + c] = 0; shrow[61 * 32 + c] = 0;
               shrow[62 * 32 + c] = 0; shrow[63 * 32 + c] = 0; }
        __builtin_amdgcn_sched_barrier(0);   // keep LDS writes before flush reads
        unsigned short* hr = h1 + (size_t)n * 2048;
#pragma unroll
        for (int i = 0; i < 4; ++i)
            *(uint4*)(hr + i * 512 + lane * 8) = *(const uint4*)&sh1[wv][i * 512 + lane * 8];
        __builtin_amdgcn_sched_barrier(0);   // flush reads before next-iter overwrites
    }
    redS[t] = sum; redQ[t] = sq;
    __syncthreads();
    if (t < 32) {
        float s = 0.f, q = 0.f;
#pragma unroll
        for (int m = 0; m < 8; ++m) { s += redS[m * 32 + t]; q += redQ[m * 32 + t]; }
        atomicAdd(&acc1[t], s);
        atomicAdd(&acc1[32 + t], q);
    }
}

// ---------------- conv2 FUSED v4: v3 + async-STAGE split (T14): prefetch sample n+stride's h1
// tile into registers before the MFMA phase, so the ~600cy global latency hides under compute.
__global__ __launch_bounds__(256) void conv2_fused(const unsigned short* __restrict__ h1,
    const unsigned short* __restrict__ w2t, const float* __restrict__ b2,
    const float* __restrict__ acc1, float count1,
    const float* __restrict__ g1, const float* __restrict__ b1n,
    unsigned short* __restrict__ z, float* __restrict__ acc2, int N)
{
    __shared__ unsigned short hbl[4][64][40];
    __shared__ unsigned short ytb[4][32][66];
    __shared__ float bcv[32], sc1[32], sh1v[32];
    __shared__ float redS[4][32], redQ[4][32];
    int t = threadIdx.x, wv = t >> 6, lane = t & 63;
    int li = lane & 15, grp = lane >> 4;
    if (t < 32) {
        bcv[t] = b2[t];
        double m = (double)acc1[t] / (double)count1;
        double v = (double)acc1[32 + t] / (double)count1 - m * m;
        float istd = (float)(1.0 / sqrt(v + 1e-5));
        float s = istd * g1[t];
        sc1[t] = s; sh1v[t] = b1n[t] - (float)m * s;
    }
    short8v af[5][2];
#pragma unroll
    for (int kk = 0; kk < 5; ++kk)
#pragma unroll
        for (int mf = 0; mf < 2; ++mf)
            af[kk][mf] = *(const short8v*)(w2t + ((kk * 32 + mf * 16 + li) * 32 + grp * 8));
    float bc[2][4];
#pragma unroll
    for (int mf = 0; mf < 2; ++mf)
#pragma unroll
        for (int r = 0; r < 4; ++r) bc[mf][r] = b2[mf * 16 + grp * 4 + r];
    float sum[2][4] = {}, sq[2][4] = {};
    __syncthreads();
    const int stride = gridDim.x * 4;
    int n = blockIdx.x * 4 + wv;
    uint4 cur[4];
    if (n < N) {
        const unsigned short* hb = h1 + (size_t)n * 2048;
#pragma unroll
        for (int i4 = 0; i4 < 4; ++i4) {
            int i = i4 * 64 + lane;
            cur[i4] = *(const uint4*)(hb + (i >> 2) * 32 + (i & 3) * 8);
        }
    }
    while (n < N) {
        int nn = n + stride;
        // stage current tile from regs: raw -> BN1 + relu (rows 1..59), pads -> 0
#pragma unroll
        for (int i4 = 0; i4 < 4; ++i4) {
            int i = i4 * 64 + lane;
            int row = i >> 2, ch0 = (i & 3) * 8;
            union { uint4 v; unsigned short u[8]; } d, o;
            d.v = cur[i4];
            if (row >= 1 && row <= 59) {
#pragma unroll
                for (int e = 0; e < 8; ++e) {
                    int c = ch0 + e;
                    float y = fmaf(sc1[c], bf2f(d.u[e]), sh1v[c]);
                    o.u[e] = f2bf(fmaxf(y, 0.f));
                }
            } else {
                o.v = (uint4){0u, 0u, 0u, 0u};
            }
            *(uint4*)&hbl[wv][row][ch0] = o.v;
        }
        __builtin_amdgcn_sched_barrier(0);
        // issue next-tile loads now; latency hides under the MFMA/pooling phase below
        if (nn < N) {
            const unsigned short* hb2 = h1 + (size_t)nn * 2048;
#pragma unroll
            for (int i4 = 0; i4 < 4; ++i4) {
                int i = i4 * 64 + lane;
                cur[i4] = *(const uint4*)(hb2 + (i >> 2) * 32 + (i & 3) * 8);
            }
        }
        __builtin_amdgcn_sched_barrier(0);
#pragma unroll
        for (int lt = 0; lt < 4; ++lt) {
            float4v acc0 = {0.f, 0.f, 0.f, 0.f}, acc1v = {0.f, 0.f, 0.f, 0.f};
#pragma unroll
            for (int kk = 0; kk < 5; ++kk) {
                int row = lt * 16 + li + kk; row = row > 63 ? 63 : row;
                short8v bf = *(const short8v*)&hbl[wv][row][grp * 8];
                acc0 = __builtin_amdgcn_mfma_f32_16x16x32_bf16(af[kk][0], bf, acc0, 0, 0, 0);
                acc1v = __builtin_amdgcn_mfma_f32_16x16x32_bf16(af[kk][1], bf, acc1v, 0, 0, 0);
            }
            if (lt * 16 + li < L2C) {
#pragma unroll
                for (int r = 0; r < 4; ++r) {
                    float y0 = acc0[r] + bc[0][r]; sum[0][r] += y0; sq[0][r] = fmaf(y0, y0, sq[0][r]);
                    float y1 = acc1v[r] + bc[1][r]; sum[1][r] += y1; sq[1][r] = fmaf(y1, y1, sq[1][r]);
                }
            }
#pragma unroll
            for (int r = 0; r < 4; ++r) {
                ytb[wv][grp * 4 + r][lt * 16 + li] = f2bf(acc0[r]);
                ytb[wv][16 + grp * 4 + r][lt * 16 + li] = f2bf(acc1v[r]);
            }
        }
        unsigned short* zr = z + (size_t)n * VEC;
        for (int s = lane; s < VEC; s += 64) {
            int c = s / 11, lo = s % 11;
            float m = bf2f(ytb[wv][c][lo * 5]);
#pragma unroll
            for (int d = 1; d < 5; ++d) m = fmaxf(m, bf2f(ytb[wv][c][lo * 5 + d]));
            zr[s] = f2bf(m + bcv[c]);          // raw pooled + bias; BN2+relu in z_pass2
        }
        __builtin_amdgcn_sched_barrier(0);
        n = nn;
    }
#pragma unroll
    for (int mf = 0; mf < 2; ++mf)
#pragma unroll
        for (int r = 0; r < 4; ++r) {
            float s = sum[mf][r], q = sq[mf][r];
#pragma unroll
            for (int m = 1; m < 16; m <<= 1) { s += __shfl_xor(s, m); q += __shfl_xor(q, m); }
            if (li == 0) { redS[wv][mf * 16 + grp * 4 + r] = s; redQ[wv][mf * 16 + grp * 4 + r] = q; }
        }
    __syncthreads();
    if (t < 32) atomicAdd(&acc2[t], redS[0][t] + redS[1][t] + redS[2][t] + redS[3][t]);
    else if (t < 64) atomicAdd(&acc2[t - 32 + 32], redQ[0][t - 32] + redQ[1][t - 32] + redQ[2][t - 32] + redQ[3][t - 32]);
}

// ---------------- z pass2: BN2 consts from acc2 in prologue; in-place BN2+relu on z ----------------
__global__ __launch_bounds__(256) void z_pass2(unsigned short* __restrict__ z,
    const float* __restrict__ acc2, float count2,
    const float* __restrict__ g2, const float* __restrict__ be2, long long total)
{
    __shared__ float sc[32], sh[32];
    int t = threadIdx.x;
    if (t < 32) {
        double m = (double)acc2[t] / (double)count2;
        double v = (double)acc2[32 + t] / (double)count2 - m * m;
        float istd = (float)(1.0 / sqrt(v + 1e-5));
        float s = istd * g2[t];
        sc[t] = s; sh[t] = be2[t] - (float)m * s;
    }
    __syncthreads();
    long long i = (long long)blockIdx.x * 256 + t;
    if (i >= total) return;
    long long n = i / 44; int r = (int)(i % 44);
    unsigned short* p = z + n * VEC + r * 8;
    union { uint4 v; unsigned short u[8]; } d;
    d.v = *(const uint4*)p;
#pragma unroll
    for (int e = 0; e < 8; ++e) {
        int c = (r * 8 + e) / 11;
        float y = fmaf(sc[c], bf2f(d.u[e]), sh[c]);
        d.u[e] = f2bf(fmaxf(y, 0.f));
    }
    *(uint4*)p = d.v;
}

// ---------------- support path (3 launches) ----------------
__global__ __launch_bounds__(128) void sup_a(const unsigned short* __restrict__ z,
    const float* __restrict__ wihf, const float* __restrict__ bihf, const float* __restrict__ bhhf,
    const float* __restrict__ wihr, const float* __restrict__ bihr, const float* __restrict__ bhhr,
    float* __restrict__ misc)
{
    __shared__ float s0[VEC], s1[VEC];
    int t = threadIdx.x, bid = blockIdx.x;
    for (int v = t; v < VEC; v += 128) {
        float a0 = 0.f, a1 = 0.f;
        for (int k = 0; k < 10; ++k) {
            a0 += bf2f(z[(size_t)k * VEC + v]);
            a1 += bf2f(z[(size_t)(10 + k) * VEC + v]);
        }
        s0[v] = a0 * 0.1f; s1[v] = a1 * 0.1f;
    }
    __syncthreads();
    if (bid == 0)
        for (int v = t; v < VEC; v += 128) { misc[128 + v] = s0[v]; misc[480 + v] = s1[v]; }
    if (bid < 11) {
        int j = bid * 128 + t;
        float a = bihf[j] + bhhf[j];
        const float* w = wihf + (size_t)j * VEC;
        for (int k = 0; k < VEC; k += 4)
            a += w[k] * s0[k] + w[k + 1] * s0[k + 1] + w[k + 2] * s0[k + 2] + w[k + 3] * s0[k + 3];
        misc[2240 + j] = a;
    } else {
        int j = (bid - 11) * 128 + t;
        float br = bihr[j] + bhhr[j];
        const float* wr = wihr + (size_t)j * VEC;
        float p1 = br, p0 = br;
        for (int k = 0; k < VEC; k += 4) {
            p1 += wr[k] * s1[k] + wr[k + 1] * s1[k + 1] + wr[k + 2] * s1[k + 2] + wr[k + 3] * s1[k + 3];
            p0 += wr[k] * s0[k] + wr[k + 1] * s0[k + 1] + wr[k + 2] * s0[k + 2] + wr[k + 3] * s0[k + 3];
        }
        misc[6464 + j] = p1;
        misc[7872 + j] = p0;
    }
}

// sup_b: local cell0 -> h1f; mode1 gates; block 0 persists h1f
__global__ __launch_bounds__(128) void sup_b(
    const float* __restrict__ wihf, const float* __restrict__ whhf,
    const float* __restrict__ bihf, const float* __restrict__ bhhf, float* __restrict__ misc)
{
    __shared__ float s1[VEC], h1f[VEC];
    int t = threadIdx.x, bid = blockIdx.x;
    for (int v = t; v < VEC; v += 128) {
        s1[v] = misc[480 + v];
        float iv = sigf(misc[2240 + v]);
        float gv = tanhf(misc[2240 + 704 + v]);
        float ov = sigf(misc[2240 + 1056 + v]);
        h1f[v] = ov * tanhf(iv * gv);
    }
    __syncthreads();
    if (bid == 0)
        for (int v = t; v < VEC; v += 128) misc[832 + v] = h1f[v];
    int j = bid * 128 + t;
    float a = bihf[j] + bhhf[j];
    const float* w = wihf + (size_t)j * VEC;
    const float* wh = whhf + (size_t)j * VEC;
    for (int k = 0; k < VEC; k += 4) {
        a += w[k] * s1[k] + w[k + 1] * s1[k + 1] + w[k + 2] * s1[k + 2] + w[k + 3] * s1[k + 3];
        a += wh[k] * h1f[k] + wh[k + 1] * h1f[k + 1] + wh[k + 2] * h1f[k + 2] + wh[k + 3] * h1f[k + 3];
    }
    misc[3648 + j] = a;
}

// sup_c: local cell0 (c1) + cell1 -> h2f/c2f; gf_const gates; block 0 persists h2f/c2f
__global__ __launch_bounds__(128) void sup_c(
    const float* __restrict__ whhf, const float* __restrict__ bihf,
    const float* __restrict__ bhhf, float* __restrict__ misc)
{
    __shared__ float h2f[VEC];
    int t = threadIdx.x, bid = blockIdx.x;
    for (int v = t; v < VEC; v += 128) {
        float iv0 = sigf(misc[2240 + v]);
        float gv0 = tanhf(misc[2240 + 704 + v]);
        float c1 = iv0 * gv0;
        float iv = sigf(misc[3648 + v]);
        float fv = sigf(misc[3648 + 352 + v]);
        float gv = tanhf(misc[3648 + 704 + v]);
        float ov = sigf(misc[3648 + 1056 + v]);
        float c2 = fv * c1 + iv * gv;
        float hh = ov * tanhf(c2);
        h2f[v] = hh;
        if (bid == 0) { misc[1536 + v] = hh; misc[1888 + v] = c2; }
    }
    __syncthreads();
    int j = bid * 128 + t;
    float a = bihf[j] + bhhf[j];
    const float* wh = whhf + (size_t)j * VEC;
    for (int k = 0; k < VEC; k += 4)
        a += wh[k] * h2f[k] + wh[k + 1] * h2f[k + 1] + wh[k + 2] * h2f[k + 2] + wh[k + 3] * h2f[k + 3];
    misc[5056 + j] = a;
}

// ---------------- W staging: 4 gates x 16 rows x 352 bf16 -> LDS (rows padded to 360, 46KB) ----------------
// Measured local optimum (72.7us). Occupancy-raising variants all regressed:
// 128q acc (r12: 102us), 2-pass 2-gate (r18: 91us), hybrid 2LDS+2global (r21: 81us).
__device__ __forceinline__ void stage_W(const unsigned short* __restrict__ Wb, int h0, int t,
                                        unsigned short (*Wlds)[16][360])
{
    for (int i = t; i < 2816; i += 256) {
        int gate = i / 704, rem = i - gate * 704;
        int row = rem / 44, ch = rem - row * 44;
        *(uint4*)&Wlds[gate][row][ch * 8] =
            *(const uint4*)(Wb + ((size_t)gate * HID + h0 + row) * VEC + ch * 8);
    }
}

// GEMM core reading W from LDS: 4 global X loads + 4 LDS W reads -> 16 MFMA per K-step.
// setprio(1) around the MFMA loop (T5): measured neutral (r27) but harmless; kept.
__device__ __forceinline__ void lstm_gemm_lds(
    const unsigned short* __restrict__ Xb,
    const unsigned short (*Wlds)[16][360],
    int q0, int li, int grp, int Q, float4v acc[4][4])
{
    const unsigned short* xp[4];
#pragma unroll
    for (int mf = 0; mf < 4; ++mf) {
        int qr = q0 + mf * 16 + li;
        if (qr > Q - 1) qr = Q - 1;
        xp[mf] = Xb + (size_t)qr * VEC + grp * 8;
    }
#pragma unroll
    for (int gi = 0; gi < 4; ++gi)
#pragma unroll
        for (int mf = 0; mf < 4; ++mf) acc[gi][mf] = (float4v){0.f, 0.f, 0.f, 0.f};
    __builtin_amdgcn_s_setprio(1);
#pragma unroll 2
    for (int ks = 0; ks < 11; ++ks) {
        int ko = ks * 32;
        short8v a0 = *(const short8v*)(xp[0] + ko);
        short8v a1 = *(const short8v*)(xp[1] + ko);
        short8v a2 = *(const short8v*)(xp[2] + ko);
        short8v a3 = *(const short8v*)(xp[3] + ko);
        short8v b0 = *(const short8v*)&Wlds[0][li][ko + grp * 8];
        short8v b1 = *(const short8v*)&Wlds[1][li][ko + grp * 8];
        short8v b2 = *(const short8v*)&Wlds[2][li][ko + grp * 8];
        short8v b3 = *(const short8v*)&Wlds[3][li][ko + grp * 8];
        acc[0][0] = __builtin_amdgcn_mfma_f32_16x16x32_bf16(a0, b0, acc[0][0], 0, 0, 0);
        acc[0][1] = __builtin_amdgcn_mfma_f32_16x16x32_bf16(a1, b0, acc[0][1], 0, 0, 0);
        acc[0][2] = __builtin_amdgcn_mfma_f32_16x16x32_bf16(a2, b0, acc[0][2], 0, 0, 0);
        acc[0][3] = __builtin_amdgcn_mfma_f32_16x16x32_bf16(a3, b0, acc[0][3], 0, 0, 0);
        acc[1][0] = __builtin_amdgcn_mfma_f32_16x16x32_bf16(a0, b1, acc[1][0], 0, 0, 0);
        acc[1][1] = __builtin_amdgcn_mfma_f32_16x16x32_bf16(a1, b1, acc[1][1], 0, 0, 0);
        acc[1][2] = __builtin_amdgcn_mfma_f32_16x16x32_bf16(a2, b1, acc[1][2], 0, 0, 0);
        acc[1][3] = __builtin_amdgcn_mfma_f32_16x16x32_bf16(a3, b1, acc[1][3], 0, 0, 0);
        acc[2][0] = __builtin_amdgcn_mfma_f32_16x16x32_bf16(a0, b2, acc[2][0], 0, 0, 0);
        acc[2][1] = __builtin_amdgcn_mfma_f32_16x16x32_bf16(a1, b2, acc[2][1], 0, 0, 0);
        acc[2][2] = __builtin_amdgcn_mfma_f32_16x16x32_bf16(a2, b2, acc[2][2], 0, 0, 0);
        acc[2][3] = __builtin_amdgcn_mfma_f32_16x16x32_bf16(a3, b2, acc[2][3], 0, 0, 0);
        acc[3][0] = __builtin_amdgcn_mfma_f32_16x16x32_bf16(a0, b3, acc[3][0], 0, 0, 0);
        acc[3][1] = __builtin_amdgcn_mfma_f32_16x16x32_bf16(a1, b3, acc[3][1], 0, 0, 0);
        acc[3][2] = __builtin_amdgcn_mfma_f32_16x16x32_bf16(a2, b3, acc[3][2], 0, 0, 0);
        acc[3][3] = __builtin_amdgcn_mfma_f32_16x16x32_bf16(a3, b3, acc[3][3], 0, 0, 0);
    }
    __builtin_amdgcn_s_setprio(0);
}

// ---------------- dual first-step kernel: y<22 -> fwd step2 (Wf), y>=22 -> bwd step0 (Wr) ----------------
__global__ __launch_bounds__(256, 4) void lstm_dual(
    const unsigned short* __restrict__ zq,
    const unsigned short* __restrict__ Wf, const unsigned short* __restrict__ Wr,
    const float* __restrict__ misc, const float* __restrict__ bihr, const float* __restrict__ bhhr,
    unsigned short* __restrict__ h3fb, unsigned short* __restrict__ hb1b,
    unsigned short* __restrict__ cb1b, int Q)
{
    __shared__ unsigned short Wlds[4][16][360];
    int t = threadIdx.x, wv = t >> 6, lane = t & 63;
    int li = lane & 15, grp = lane >> 4;
    int q0 = blockIdx.x * 256 + wv * 64;
    int fwd = (blockIdx.y < 22);
    int h0 = (fwd ? blockIdx.y : blockIdx.y - 22) * 16;
    int h = h0 + li;
    stage_W(fwd ? Wf : Wr, h0, t, Wlds);
    __syncthreads();
    float4v acc[4][4];
    lstm_gemm_lds(zq, Wlds, q0, li, grp, Q, acc);
    if (fwd) {
        float ai = misc[5056 + h], afv = misc[5056 + HID + h];
        float ag = misc[5056 + 2 * HID + h], ao = misc[5056 + 3 * HID + h];
        float cc1 = misc[1888 + h];
#pragma unroll
        for (int mf = 0; mf < 4; ++mf)
#pragma unroll
            for (int r = 0; r < 4; ++r) {
                int q = q0 + mf * 16 + grp * 4 + r;
                if (q >= Q) continue;
                float iv = sigf(acc[0][mf][r] + ai);
                float fv = sigf(acc[1][mf][r] + afv);
                float gv = ftanh(acc[2][mf][r] + ag);
                float ov = sigf(acc[3][mf][r] + ao);
                float cn = fmaf(fv, cc1, iv * gv);
                h3fb[(size_t)q * HID + h] = f2bf(ov * ftanh(cn));
            }
    } else {
        float ai = bihr[h] + bhhr[h];
        float ag = bihr[2 * HID + h] + bhhr[2 * HID + h];
        float ao = bihr[3 * HID + h] + bhhr[3 * HID + h];
#pragma unroll
        for (int mf = 0; mf < 4; ++mf)
#pragma unroll
            for (int r = 0; r < 4; ++r) {
                int q = q0 + mf * 16 + grp * 4 + r;
                if (q >= Q) continue;
                float iv = sigf(acc[0][mf][r] + ai);
                float gv = ftanh(acc[2][mf][r] + ag);
                float ov = sigf(acc[3][mf][r] + ao);
                float cn = iv * gv;
                hb1b[(size_t)q * HID + h] = f2bf(ov * ftanh(cn));
                cb1b[(size_t)q * HID + h] = f2bf(cn);
            }
    }
}

// ---------------- recurrent LSTM step: gates = hprev@Wh + add1 ; cprev bf16 per-q ----------------
__global__ __launch_bounds__(256, 4) void lstm_mfma(
    const unsigned short* __restrict__ Xb, const unsigned short* __restrict__ Wb,
    const float* __restrict__ add1, const unsigned short* __restrict__ cprevb,
    unsigned short* __restrict__ hbf, unsigned short* __restrict__ cbf, int Q)
{
    __shared__ unsigned short Wlds[4][16][360];
    int t = threadIdx.x, wv = t >> 6, lane = t & 63;
    int li = lane & 15, grp = lane >> 4;
    int q0 = blockIdx.x * 256 + wv * 64;
    int h0 = blockIdx.y * 16;
    int h = h0 + li;
    stage_W(Wb, h0, t, Wlds);
    __syncthreads();
    float4v acc[4][4];
    lstm_gemm_lds(Xb, Wlds, q0, li, grp, Q, acc);
    float ai = add1[h], afv = add1[HID + h], ag = add1[2 * HID + h], ao = add1[3 * HID + h];
#pragma unroll
    for (int mf = 0; mf < 4; ++mf) {
#pragma unroll
        for (int r = 0; r < 4; ++r) {
            int q = q0 + mf * 16 + grp * 4 + r;
            if (q >= Q) continue;
            float iv = sigf(acc[0][mf][r] + ai);
            float fv = sigf(acc[1][mf][r] + afv);
            float gv = ftanh(acc[2][mf][r] + ag);
            float ov = sigf(acc[3][mf][r] + ao);
            float cp = bf2f(cprevb[(size_t)q * HID + h]);
            float cn = fmaf(fv, cp, iv * gv);
            float hn = ov * ftanh(cn);
            hbf[(size_t)q * HID + h] = f2bf(hn);
            if (cbf) cbf[(size_t)q * HID + h] = f2bf(cn);
        }
    }
}

// ---------------- cosine sims + softmax; one wave per query (bf16 h inputs) ----------------
__global__ __launch_bounds__(256) void final_sims(
    const unsigned short* __restrict__ h3f, const unsigned short* __restrict__ hb1,
    const unsigned short* __restrict__ hb2, const unsigned short* __restrict__ hb3,
    const float* __restrict__ misc, float* __restrict__ out, int Q)
{
    int t = threadIdx.x;
    int wave = t >> 6, lane = t & 63;
    int q = blockIdx.x * 4 + wave;
    if (q >= Q) return;
    const unsigned short* a3 = h3f + (size_t)q * HID;
    const unsigned short* b1 = hb1 + (size_t)q * HID;
    const unsigned short* b2 = hb2 + (size_t)q * HID;
    const unsigned short* b3 = hb3 + (size_t)q * HID;
    const float* h1c = misc + 832;
    const float* h2c = misc + 1536;
    float sA = 0, sB = 0, s3 = 0, s4 = 0, s5 = 0, s6 = 0, s7 = 0, s8 = 0, s9 = 0, s10 = 0;
    for (int hh = lane; hh < HID; hh += 64) {
        float a = bf2f(a3[hh]), b = bf2f(b1[hh]), v2 = bf2f(b2[hh]), v3 = bf2f(b3[hh]);
        float u1 = h1c[hh], u2 = h2c[hh];
        sA += u1 * a;  sB += u2 * a;
        s3 += a * a;   s4 += b * b;
        s5 += v3 * b;  s6 += v2 * b;
        s7 += v3 * v3; s8 += v2 * v2;
        s9 += u1 * u1; s10 += u2 * u2;
    }
#pragma unroll
    for (int off = 32; off > 0; off >>= 1) {
        sA += __shfl_xor(sA, off);  sB += __shfl_xor(sB, off);
        s3 += __shfl_xor(s3, off);  s4 += __shfl_xor(s4, off);
        s5 += __shfl_xor(s5, off);  s6 += __shfl_xor(s6, off);
        s7 += __shfl_xor(s7, off);  s8 += __shfl_xor(s8, off);
        s9 += __shfl_xor(s9, off);  s10 += __shfl_xor(s10, off);
    }
    if (lane == 0) {
        float nq  = fmaxf(sqrtf(s3 + s4), 1e-8f);
        float ns0 = fmaxf(sqrtf(s9 + s7), 1e-8f);
        float ns1 = fmaxf(sqrtf(s10 + s8), 1e-8f);
        float sim0 = (sA + s5) / (ns0 * nq);
        float sim1 = (sB + s6) / (ns1 * nq);
        float mx = fmaxf(sim0, sim1);
        float e0 = __expf(sim0 - mx), e1 = __expf(sim1 - mx);
        float inv = 1.f / (e0 + e1);
        out[(size_t)q * 2 + 0] = e0 * inv;
        out[(size_t)q * 2 + 1] = e1 * inv;
    }
}

extern "C" void kernel_launch(void* const* d_in, const int* in_sizes, int n_in,
                              void* d_out, int out_size, void* d_ws, size_t ws_size,
                              hipStream_t stream)
{
    const float* x    = (const float*)d_in[0];
    const float* c1w  = (const float*)d_in[1];
    const float* c1b  = (const float*)d_in[2];
    const float* bn1g = (const float*)d_in[3];
    const float* bn1b = (const float*)d_in[4];
    const float* c2w  = (const float*)d_in[5];
    const float* c2b  = (const float*)d_in[6];
    const float* bn2g = (const float*)d_in[7];
    const float* bn2b = (const float*)d_in[8];
    const float* wihf = (const float*)d_in[9];
    const float* whhf = (const float*)d_in[10];
    const float* bihf = (const float*)d_in[11];
    const float* bhhf = (const float*)d_in[12];
    const float* wihr = (const float*)d_in[13];
    const float* whhr = (const float*)d_in[14];
    const float* bihr = (const float*)d_in[15];
    const float* bhhr = (const float*)d_in[16];

    int N = in_sizes[0] / LIN;
    int Q = N - NSUP;

    char* ws = (char*)d_ws;
    float* acc1  = (float*)(ws + 0);                       // 64 f32 stats accumulators (conv1)
    float* acc2  = (float*)(ws + 256);                     // 64 f32 stats accumulators (conv2)
    float* misc  = (float*)(ws + 1048576);                 // ~10.7K f32
    unsigned short* w2t = (unsigned short*)(ws + 1114112); // 5120 bf16
    unsigned short* Wf  = (unsigned short*)(ws + 2097152); // 1408*352 bf16
    unsigned short* Wr  = (unsigned short*)(ws + 3145728);
    unsigned short* Wh  = (unsigned short*)(ws + 4194304);
    unsigned short* z   = (unsigned short*)(ws + 5242880); // N*352 bf16
    unsigned short* h1  = (unsigned short*)(ws + 17825792);// N*64*32 bf16 (dead after conv2)
    const size_t Sb = (size_t)Q * HID * sizeof(unsigned short);   // ~11.5MB
    unsigned short* h3fb = (unsigned short*)(ws + 17825792);      // over h1 (dead)
    unsigned short* hb1b = (unsigned short*)(ws + 17825792 + Sb);
    unsigned short* cb1b = (unsigned short*)(ws + 17825792 + 2 * Sb);
    unsigned short* hb2b = (unsigned short*)(ws + 17825792 + 3 * Sb);
    unsigned short* cb2b = (unsigned short*)(ws + 17825792 + 4 * Sb);
    unsigned short* hb3b = (unsigned short*)(ws + 17825792 + 5 * Sb);

    // 0. zero the stats accumulators (capture-safe async memset)
    hipMemsetAsync(acc1, 0, 512, stream);
    // 1. cast weights
    {
        int tot = 3 * GATES * VEC + 5120;
        cast_weights<<<(tot + 255) / 256, 256, 0, stream>>>(wihf, wihr, whhr, c2w, Wf, Wr, Wh, w2t);
    }
    // 2. conv1 v3: stats (atomic) + pooled raw, x row staged in LDS (cooperative)
    conv1_pass1<<<NBLK, 256, 0, stream>>>(x, c1w, c1b, acc1, h1, N);
    // 3. conv2 fused v4: BN1 consts from acc1; reg-prefetch next tile; one MFMA pass -> acc2 + raw z
    conv2_fused<<<NBLK, 256, 0, stream>>>(h1, w2t, c2b, acc1, (float)((long long)N * L1C),
                                          bn1g, bn1b, z, acc2, N);
    // 4. z BN2+relu in place (BN2 consts from acc2)
    {
        long long total = (long long)N * 44;
        z_pass2<<<(unsigned)((total + 255) / 256), 256, 0, stream>>>(z, acc2, (float)((long long)N * L2C),
                                                                     bn2g, bn2b, total);
    }
    // 5. support path (3 launches)
    sup_a<<<22, 128, 0, stream>>>(z, wihf, bihf, bhhf, wihr, bihr, bhhr, misc);
    sup_b<<<11, 128, 0, stream>>>(wihf, whhf, bihf, bhhf, misc);
    sup_c<<<11, 128, 0, stream>>>(whhf, bihf, bhhf, misc);
    // 6. big LSTM steps (bf16 h/c state), 64q per wave / 256q per block, W staged via LDS + setprio
    const unsigned short* zq = z + (size_t)NSUP * VEC;
    int gx = (Q + 255) / 256;
    lstm_dual<<<dim3(gx, 44), 256, 0, stream>>>(zq, Wf, Wr, misc, bihr, bhhr, h3fb, hb1b, cb1b, Q);
    lstm_mfma<<<dim3(gx, 22), 256, 0, stream>>>(hb1b, Wh, misc + 6464, cb1b, hb2b, cb2b, Q);
    lstm_mfma<<<dim3(gx, 22), 256, 0, stream>>>(hb2b, Wh, misc + 7872, cb2b, hb3b, nullptr, Q);
    // 7. sims + softmax
    final_sims<<<(Q + 3) / 4, 256, 0, stream>>>(h3fb, hb1b, hb2b, hb3b, misc, (float*)d_out, Q);
}